// Round 1
// 687.980 us; speedup vs baseline: 1.0013x; 1.0013x over previous
//
#include <hip/hip_runtime.h>
#include <stdint.h>

// ---------------------------------------------------------------------------
// RelativeEncoderLayer. Round 5 (R4 + one change):
//  - gemm_bt: staging switched from register-staged (global->VGPR->ds_write)
//    to direct async global->LDS via __builtin_amdgcn_global_load_lds width=16
//    (m97 pattern: LDS layout is already linear-in-tid = wave base + lane*16,
//    so the HW write pattern matches exactly). Expect ~646 -> ~874 TF.
//  - attn_flash / tcast / cast4 / vtrans / ln_res: untouched.
// ---------------------------------------------------------------------------

typedef __bf16 bf16x8 __attribute__((ext_vector_type(8)));
typedef float  f32x4  __attribute__((ext_vector_type(4)));

__device__ __forceinline__ unsigned short f2bf(float f) {
  union { float f; unsigned u; } x; x.f = f;
  unsigned r = x.u + 0x7fffu + ((x.u >> 16) & 1u);   // RNE
  return (unsigned short)(r >> 16);
}
__device__ __forceinline__ float bf2f(unsigned short h) {
  union { unsigned u; float f; } x; x.u = ((unsigned)h) << 16; return x.f;
}

// Direct async global->LDS, 16B per lane. LDS dest is wave-uniform base +
// lane*16 (HW-fixed pattern); global src is per-lane.
__device__ __forceinline__ void gload_lds16(
    const unsigned short* g,
    __attribute__((address_space(3))) unsigned int* l) {
  __builtin_amdgcn_global_load_lds(
      (const __attribute__((address_space(1))) unsigned int*)g, l, 16, 0, 0);
}

// ---------------------------------------------------------------------------
// GEMM: C[M,N] = A[M,K] @ Bt[N,K]^T + bias, 128x128 tile, BK=32,
// 4 waves of 64x64, global_load_lds staging (m97-proven structure).
// EPI: 0 = bias->bf16, 1 = bias->f32, 2 = bias+relu->bf16
// ---------------------------------------------------------------------------
template<int EPI>
__global__ __launch_bounds__(256) void gemm_bt(
    const unsigned short* __restrict__ A,
    const unsigned short* __restrict__ Bt,
    const float* __restrict__ bias,
    void* __restrict__ Cout,
    int M, int N, int K)
{
  __shared__ __align__(16) unsigned short As[128 * 32];
  __shared__ __align__(16) unsigned short Bs[128 * 32];
  const int tid = threadIdx.x;
  const int lane = tid & 63, wv = tid >> 6;
  const int lq = lane >> 4, lm = lane & 15;
  const int wr = wv >> 1, wc = wv & 1;
  const int m0 = blockIdx.y * 128, n0 = blockIdx.x * 128;

  const unsigned short* ga0 = A  + (size_t)(m0 + (tid >> 2)) * K + (tid & 3) * 8;
  const unsigned short* gb0 = Bt + (size_t)(n0 + (tid >> 2)) * K + (tid & 3) * 8;
  const size_t rstep = (size_t)64 * K;

  // Wave-uniform LDS staging bases: wave wv writes rows wv*16..wv*16+15
  // (1 KiB = 256 uints); +1024 uints = +4096 B = rows 64+.
  __attribute__((address_space(3))) unsigned int* lA =
      (__attribute__((address_space(3))) unsigned int*)As + wv * 256;
  __attribute__((address_space(3))) unsigned int* lB =
      (__attribute__((address_space(3))) unsigned int*)Bs + wv * 256;

  const char* fa = (const char*)As + (wr * 64 + lm) * 64 + lq * 16;
  const char* fb = (const char*)Bs + (wc * 64 + lm) * 64 + lq * 16;

  f32x4 acc[4][4] = {};
  const int nk = K >> 5;
  for (int kt = 0; kt < nk; ++kt) {
    __syncthreads();                 // all waves done reading previous tile
    gload_lds16(ga0,         lA);
    gload_lds16(ga0 + rstep, lA + 1024);
    gload_lds16(gb0,         lB);
    gload_lds16(gb0 + rstep, lB + 1024);
    ga0 += 32; gb0 += 32;
    __syncthreads();                 // compiler drains vmcnt before barrier
    bf16x8 af[4], bfr[4];
    #pragma unroll
    for (int i = 0; i < 4; ++i) af[i]  = *(const bf16x8*)(fa + i * 16 * 64);
    #pragma unroll
    for (int j = 0; j < 4; ++j) bfr[j] = *(const bf16x8*)(fb + j * 16 * 64);
    #pragma unroll
    for (int i = 0; i < 4; ++i)
      #pragma unroll
      for (int j = 0; j < 4; ++j)
        acc[i][j] = __builtin_amdgcn_mfma_f32_16x16x32_bf16(af[i], bfr[j], acc[i][j], 0, 0, 0);
  }
  #pragma unroll
  for (int i = 0; i < 4; ++i) {
    #pragma unroll
    for (int j = 0; j < 4; ++j) {
      const int col = n0 + wc * 64 + j * 16 + lm;
      const float bv = bias[col];
      #pragma unroll
      for (int r = 0; r < 4; ++r) {
        const int row = m0 + wr * 64 + i * 16 + lq * 4 + r;
        float v = acc[i][j][r] + bv;
        if (EPI == 2) v = fmaxf(v, 0.0f);
        if (EPI == 1) ((float*)Cout)[(size_t)row * N + col] = v;
        else ((unsigned short*)Cout)[(size_t)row * N + col] = f2bf(v);
      }
    }
  }
}

// ---------------------------------------------------------------------------
// Transpose-cast: out[C][R] bf16 = in[R][C] fp32.  32x32 LDS tiles.
// ---------------------------------------------------------------------------
__global__ __launch_bounds__(256) void tcast(
    const float* __restrict__ in, unsigned short* __restrict__ out, int R, int C)
{
  __shared__ float tile[32][33];
  const int tx = threadIdx.x & 31, ty = threadIdx.x >> 5;
  const int r0 = blockIdx.y * 32, c0 = blockIdx.x * 32;
  #pragma unroll
  for (int s = 0; s < 4; ++s)
    tile[ty + s * 8][tx] = in[(size_t)(r0 + ty + s * 8) * C + c0 + tx];
  __syncthreads();
  #pragma unroll
  for (int s = 0; s < 4; ++s)
    out[(size_t)(c0 + ty + s * 8) * R + r0 + tx] = f2bf(tile[tx][ty + s * 8]);
}

__global__ __launch_bounds__(256) void cast4(
    const float* __restrict__ in, unsigned short* __restrict__ out, int n)
{
  int i = (blockIdx.x * 256 + threadIdx.x) * 4;
  if (i < n) {
    float4 v = *(const float4*)(in + i);
    ushort4 o;
    o.x = f2bf(v.x); o.y = f2bf(v.y); o.z = f2bf(v.z); o.w = f2bf(v.w);
    *(ushort4*)(out + i) = o;
  }
}

// ---------------------------------------------------------------------------
// V-transpose: VP[8192 tok][1024] bf16 -> VPT[h][d][b][1024 pos] bf16.
// ---------------------------------------------------------------------------
__global__ __launch_bounds__(256) void vtrans(
    const unsigned short* __restrict__ VP, unsigned short* __restrict__ VPT)
{
  __shared__ unsigned short tile[64 * 66];
  const int pt = blockIdx.x, h = blockIdx.y, b = blockIdx.z;
  const int tid = threadIdx.x;
  const int p = tid >> 2, c0 = (tid & 3) * 16;
  const unsigned short* src = VP + (size_t)(b * 1024 + pt * 64 + p) * 1024 + h * 64 + c0;
  union { uint4 q; unsigned int u[4]; } t0, t1;
  t0.q = *(const uint4*)src;
  t1.q = *(const uint4*)(src + 8);
  #pragma unroll
  for (int e = 0; e < 4; ++e) {
    *(unsigned int*)&tile[p * 66 + c0 + e * 2]     = t0.u[e];
    *(unsigned int*)&tile[p * 66 + c0 + 8 + e * 2] = t1.u[e];
  }
  __syncthreads();
  const int d = tid >> 2, p0 = (tid & 3) * 16;
  union { uint4 q[2]; unsigned short s[16]; } ob;
  #pragma unroll
  for (int e = 0; e < 16; ++e) ob.s[e] = tile[(p0 + e) * 66 + d];
  unsigned short* dst = VPT + ((size_t)(h * 64 + d) * 8 + b) * 1024 + pt * 64 + p0;
  *(uint4*)dst       = ob.q[0];
  *(uint4*)(dst + 8) = ob.q[1];
}

// ---------------------------------------------------------------------------
// Flash attention with Shaw rel-pos, no-max softmax (|s| < ~2.5 -> exp safe,
// math-identical to softmax).  64 Q-rows/block, 64-wide K tiles, 16 rows/wave.
// Qrel computed in-kernel: Srel = Q_tile @ rel_k^T via 6 MFMAs (bins 0..32),
// written to wave-private qrel_s rows.  Bins 0/32 (clip) in registers; bins
// 1..31 hit exactly once per q-row.  Epilogue: R[64x32] @ rel_v as one MFMA
// per d-tile + scalar bin-32 term.
// ---------------------------------------------------------------------------
__global__ __launch_bounds__(256, 3) void attn_flash(
    const unsigned short* __restrict__ Qp,
    const unsigned short* __restrict__ Kp,
    const unsigned short* __restrict__ VPT,
    const float* __restrict__ relk,
    const float* __restrict__ relv,
    unsigned short* __restrict__ ctx)
{
  const int qt = blockIdx.x, h = blockIdx.y, b = blockIdx.z;
  const int tid = threadIdx.x;
  const int lane = tid & 63, wv = tid >> 6;
  const int lq = lane >> 4, lm = lane & 15;

  __shared__ __align__(16) unsigned short Kt[64][72];   // [pos][d]
  __shared__ __align__(16) unsigned short Vt[64][72];   // [d][pos]
  __shared__ __align__(16) unsigned short Pt[64][72];   // [qrow][pos] / RaccB
  __shared__ __align__(16) unsigned short relvT[64][32];// [d][bin 0..31] bf16
  __shared__ float qrel_s[64][33];
  __shared__ float Racc[64][33];

  const int tok0 = b * 1024 + qt * 64;

  for (int i = tid; i < 64 * 33; i += 256) {
    const int rr = i / 33, ss = i - rr * 33;
    Racc[rr][ss] = 0.0f;
  }
  for (int i = tid; i < 64 * 32; i += 256) {
    const int dd = i >> 5, ss = i & 31;
    relvT[dd][ss] = f2bf(relv[ss * 64 + dd]);
  }

  // Q fragments (A-layout): rows wv*16+lm, d = {lq*8.., 32+lq*8..}
  bf16x8 qf0, qf1;
  {
    const unsigned short* qg = Qp + (size_t)(tok0 + wv * 16 + lm) * 1024 + h * 64;
    qf0 = *(const bf16x8*)(qg + lq * 8);
    qf1 = *(const bf16x8*)(qg + 32 + lq * 8);
  }

  // Srel = Q @ rel_k^T  (bins 0..32; tiles of 16 bins, zero-padded)
  #pragma unroll
  for (int t = 0; t < 3; ++t) {
    const int bin = t * 16 + lm;
    union { bf16x8 v; unsigned short s[8]; } rk0, rk1;
    #pragma unroll
    for (int e = 0; e < 8; ++e) { rk0.s[e] = 0; rk1.s[e] = 0; }
    if (bin < 33) {
      const float* rp = relk + bin * 64 + lq * 8;
      #pragma unroll
      for (int e = 0; e < 8; ++e) {
        rk0.s[e] = f2bf(rp[e]);
        rk1.s[e] = f2bf(rp[32 + e]);
      }
    }
    f32x4 Sr = {};
    Sr = __builtin_amdgcn_mfma_f32_16x16x32_bf16(qf0, rk0.v, Sr, 0, 0, 0);
    Sr = __builtin_amdgcn_mfma_f32_16x16x32_bf16(qf1, rk1.v, Sr, 0, 0, 0);
    if (bin < 33) {
      #pragma unroll
      for (int r = 0; r < 4; ++r) qrel_s[wv * 16 + lq * 4 + r][bin] = Sr[r];
    }
  }
  __syncthreads();

  float e0f[4], e32f[4];
  #pragma unroll
  for (int r = 0; r < 4; ++r) {
    const int rowl = wv * 16 + lq * 4 + r;
    e0f[r]  = __expf(qrel_s[rowl][0]  * 0.125f);
    e32f[r] = __expf(qrel_s[rowl][32] * 0.125f);
  }

  f32x4 Oa[4] = {};
  float rsum[4] = {0, 0, 0, 0}, r0a[4] = {0, 0, 0, 0}, r32a[4] = {0, 0, 0, 0};

  const int srow = tid >> 2, scol = (tid & 3) * 16;
  const unsigned short* kg = Kp + (size_t)(b * 1024 + srow) * 1024 + h * 64 + scol;
  const unsigned short* vg = VPT + ((size_t)(h * 64 + srow) * 8 + b) * 1024 + scol;
  const int qa0 = qt * 64 + wv * 16;          // first absolute q-row of this wave

  for (int kt = 0; kt < 16; ++kt) {
    __syncthreads();
    *(uint4*)&Kt[srow][scol]     = *(const uint4*)(kg);
    *(uint4*)&Kt[srow][scol + 8] = *(const uint4*)(kg + 8);
    *(uint4*)&Vt[srow][scol]     = *(const uint4*)(vg);
    *(uint4*)&Vt[srow][scol + 8] = *(const uint4*)(vg + 8);
    kg += 64 * 1024;
    vg += 64;
    __syncthreads();

    #pragma unroll
    for (int tj = 0; tj < 4; ++tj) {
      bf16x8 kf0 = *(const bf16x8*)(&Kt[tj * 16 + lm][lq * 8]);
      bf16x8 kf1 = *(const bf16x8*)(&Kt[tj * 16 + lm][32 + lq * 8]);
      f32x4 S = {};
      S = __builtin_amdgcn_mfma_f32_16x16x32_bf16(qf0, kf0, S, 0, 0, 0);
      S = __builtin_amdgcn_mfma_f32_16x16x32_bf16(qf1, kf1, S, 0, 0, 0);
      const int c0 = kt * 64 + tj * 16;
      if (c0 + 31 <= qa0) {
        #pragma unroll
        for (int r = 0; r < 4; ++r) {
          const float p = __expf(S[r] * 0.125f) * e0f[r];
          r0a[r] += p; rsum[r] += p;
          Pt[wv * 16 + lq * 4 + r][tj * 16 + lm] = f2bf(p);
        }
      } else if (c0 >= qa0 + 31) {
        #pragma unroll
        for (int r = 0; r < 4; ++r) {
          const float p = __expf(S[r] * 0.125f) * e32f[r];
          r32a[r] += p; rsum[r] += p;
          Pt[wv * 16 + lq * 4 + r][tj * 16 + lm] = f2bf(p);
        }
      } else {
        const int kpos = c0 + lm;
        #pragma unroll
        for (int r = 0; r < 4; ++r) {
          const int rowl = wv * 16 + lq * 4 + r;
          const int dist = kpos - (qt * 64 + rowl);
          const int bin = (dist < -16 ? 0 : (dist > 16 ? 32 : dist + 16));
          const float p = __expf((S[r] + qrel_s[rowl][bin]) * 0.125f);
          rsum[r] += p;
          if (bin == 0)       r0a[r]  += p;
          else if (bin == 32) r32a[r] += p;
          else Racc[rowl][bin] = p;      // each (row,bin 1..31) hit exactly once
          Pt[rowl][tj * 16 + lm] = f2bf(p);
        }
      }
    }
    __syncthreads();   // order ALL P-stores before P.V fragment reads
    #pragma unroll
    for (int dt = 0; dt < 4; ++dt) {
      #pragma unroll
      for (int kc = 0; kc < 2; ++kc) {
        bf16x8 pf = *(const bf16x8*)(&Pt[wv * 16 + lm][kc * 32 + lq * 8]);
        bf16x8 vf = *(const bf16x8*)(&Vt[dt * 16 + lm][kc * 32 + lq * 8]);
        Oa[dt] = __builtin_amdgcn_mfma_f32_16x16x32_bf16(pf, vf, Oa[dt], 0, 0, 0);
      }
    }
  }

  // reduce per-lane partials across the 16 lanes sharing each row
  #pragma unroll
  for (int r = 0; r < 4; ++r) {
    #pragma unroll
    for (int off = 1; off < 16; off <<= 1) {
      rsum[r] += __shfl_xor(rsum[r], off, 64);
      r0a[r]  += __shfl_xor(r0a[r],  off, 64);
      r32a[r] += __shfl_xor(r32a[r], off, 64);
    }
  }
  if (lm == 0) {
    #pragma unroll
    for (int r = 0; r < 4; ++r) Racc[wv * 16 + lq * 4 + r][0] = r0a[r];
  }
  __syncthreads();
  for (int i = tid; i < 64 * 32; i += 256) {
    const int rr = i >> 5, cc = i & 31;
    Pt[rr][cc] = f2bf(Racc[rr][cc]);
  }
  __syncthreads();

  bf16x8 raf = *(const bf16x8*)(&Pt[wv * 16 + lm][lq * 8]);
  #pragma unroll
  for (int dt = 0; dt < 4; ++dt) {
    bf16x8 rvb = *(const bf16x8*)(&relvT[dt * 16 + lm][lq * 8]);
    f32x4 O2 = {};
    O2 = __builtin_amdgcn_mfma_f32_16x16x32_bf16(raf, rvb, O2, 0, 0, 0);
    const float rv32 = relv[32 * 64 + dt * 16 + lm];
    #pragma unroll
    for (int r = 0; r < 4; ++r) {
      const int rowl = wv * 16 + lq * 4 + r;
      const float v = (Oa[dt][r] + O2[r] + r32a[r] * rv32) / rsum[r];
      ctx[(size_t)(tok0 + rowl) * 1024 + h * 64 + dt * 16 + lm] = f2bf(v);
    }
  }
}

// ---------------------------------------------------------------------------
// LayerNorm with residual: y = LN(x + res)*g + b -> fp32 (and optional bf16)
// ---------------------------------------------------------------------------
template<bool WB>
__global__ __launch_bounds__(256) void ln_res(
    const float* __restrict__ x, const float* __restrict__ res,
    const float* __restrict__ g, const float* __restrict__ bta,
    float* __restrict__ of, unsigned short* __restrict__ ob)
{
  const int row = blockIdx.x;
  const int tid = threadIdx.x;
  __shared__ float buf[1024];
  __shared__ float red[8];
  float s1 = 0.f, s2 = 0.f;
  for (int i = tid; i < 1024; i += 256) {
    const float v = x[(size_t)row * 1024 + i] + res[(size_t)row * 1024 + i];
    buf[i] = v; s1 += v; s2 += v * v;
  }
  #pragma unroll
  for (int off = 1; off < 64; off <<= 1) {
    s1 += __shfl_xor(s1, off, 64);
    s2 += __shfl_xor(s2, off, 64);
  }
  const int wv = tid >> 6;
  if ((tid & 63) == 0) { red[wv * 2] = s1; red[wv * 2 + 1] = s2; }
  __syncthreads();
  s1 = red[0] + red[2] + red[4] + red[6];
  s2 = red[1] + red[3] + red[5] + red[7];
  const float mean = s1 * (1.f / 1024.f);
  const float var = s2 * (1.f / 1024.f) - mean * mean;
  const float rstd = rsqrtf(var + 1e-6f);
  for (int i = tid; i < 1024; i += 256) {
    const float y = (buf[i] - mean) * rstd * g[i] + bta[i];
    of[(size_t)row * 1024 + i] = y;
    if (WB) ob[(size_t)row * 1024 + i] = f2bf(y);
  }
}

// ---------------------------------------------------------------------------
extern "C" void kernel_launch(void* const* d_in, const int* in_sizes, int n_in,
                              void* d_out, int out_size, void* d_ws, size_t ws_size,
                              hipStream_t stream) {
  (void)in_sizes; (void)n_in; (void)out_size; (void)ws_size;
  const float* q    = (const float*)d_in[0];
  const float* k    = (const float*)d_in[1];
  const float* v    = (const float*)d_in[2];
  const float* wq   = (const float*)d_in[3];
  const float* bq   = (const float*)d_in[4];
  const float* wk   = (const float*)d_in[5];
  const float* bk   = (const float*)d_in[6];
  const float* wv_  = (const float*)d_in[7];
  const float* bv   = (const float*)d_in[8];
  const float* wfc  = (const float*)d_in[9];
  const float* bfc  = (const float*)d_in[10];
  const float* w1   = (const float*)d_in[11];
  const float* b1   = (const float*)d_in[12];
  const float* w2   = (const float*)d_in[13];
  const float* b2   = (const float*)d_in[14];
  const float* ln_g = (const float*)d_in[15];
  const float* ln_b = (const float*)d_in[16];
  const float* rel_k = (const float*)d_in[17];
  const float* rel_v = (const float*)d_in[18];

  char* ws = (char*)d_ws;
  const size_t MB = 1ull << 20;
  unsigned short* WQT  = (unsigned short*)(ws + 0 * MB);
  unsigned short* WKT  = (unsigned short*)(ws + 2 * MB);
  unsigned short* WVT  = (unsigned short*)(ws + 4 * MB);
  unsigned short* WFCT = (unsigned short*)(ws + 6 * MB);
  unsigned short* W1T  = (unsigned short*)(ws + 8 * MB);    // [4096][1024]
  unsigned short* W2T  = (unsigned short*)(ws + 16 * MB);   // [1024][4096]
  unsigned short* QP   = (unsigned short*)(ws + 24 * MB);   // [24,40)
  unsigned short* KP   = (unsigned short*)(ws + 40 * MB);   // [40,56)
  unsigned short* VP   = (unsigned short*)(ws + 56 * MB);   // [56,72)
  unsigned short* QBF  = (unsigned short*)(ws + 72 * MB);   // [72,88)
  unsigned short* KBF  = (unsigned short*)(ws + 88 * MB);   // [88,104)
  unsigned short* VBF  = (unsigned short*)(ws + 104 * MB);  // [104,120)
  // lifetime reuse (all producers strictly after the region's last reader):
  unsigned short* VPT  = QBF;                               // [72,88)
  unsigned short* CTX  = KBF;                               // [88,104)
  float*          OTMP = (float*)(ws + 104 * MB);           // [104,136)
  float*          X1F  = (float*)(ws + 24 * MB);            // [24,56)
  unsigned short* X1BF = VP;                                // [56,72)
  unsigned short* HBUF = (unsigned short*)(ws + 72 * MB);   // [72,136)
  float*          Y2   = (float*)(ws + 136 * MB);           // [136,168)

  const dim3 blk(256);
  const int NTOK = 8192;

  tcast<<<dim3(32, 32), blk, 0, stream>>>(wq, WQT, 1024, 1024);
  tcast<<<dim3(32, 32), blk, 0, stream>>>(wk, WKT, 1024, 1024);
  tcast<<<dim3(32, 32), blk, 0, stream>>>(wv_, WVT, 1024, 1024);
  tcast<<<dim3(32, 32), blk, 0, stream>>>(wfc, WFCT, 1024, 1024);
  tcast<<<dim3(128, 32), blk, 0, stream>>>(w1, W1T, 1024, 4096);
  tcast<<<dim3(32, 128), blk, 0, stream>>>(w2, W2T, 4096, 1024);
  cast4<<<8192, blk, 0, stream>>>(q, QBF, NTOK * 1024);
  cast4<<<8192, blk, 0, stream>>>(k, KBF, NTOK * 1024);
  cast4<<<8192, blk, 0, stream>>>(v, VBF, NTOK * 1024);

  gemm_bt<0><<<dim3(8, 64), blk, 0, stream>>>(QBF, WQT, bq, QP, NTOK, 1024, 1024);
  gemm_bt<0><<<dim3(8, 64), blk, 0, stream>>>(KBF, WKT, bk, KP, NTOK, 1024, 1024);
  gemm_bt<0><<<dim3(8, 64), blk, 0, stream>>>(VBF, WVT, bv, VP, NTOK, 1024, 1024);

  vtrans<<<dim3(16, 16, 8), blk, 0, stream>>>(VP, VPT);

  attn_flash<<<dim3(16, 16, 8), blk, 0, stream>>>(QP, KP, VPT, rel_k, rel_v, CTX);

  gemm_bt<1><<<dim3(8, 64), blk, 0, stream>>>(CTX, WFCT, bfc, OTMP, NTOK, 1024, 1024);
  ln_res<true><<<8192, blk, 0, stream>>>(OTMP, q, ln_g, ln_b, X1F, X1BF);
  gemm_bt<2><<<dim3(32, 64), blk, 0, stream>>>(X1BF, W1T, b1, HBUF, NTOK, 4096, 1024);
  gemm_bt<1><<<dim3(8, 64), blk, 0, stream>>>(HBUF, W2T, b2, Y2, NTOK, 1024, 4096);
  ln_res<false><<<8192, blk, 0, stream>>>(Y2, X1F, ln_g, ln_b, (float*)d_out, nullptr);
}

// Round 2
// 659.839 us; speedup vs baseline: 1.0440x; 1.0426x over previous
//
#include <hip/hip_runtime.h>
#include <stdint.h>

// ---------------------------------------------------------------------------
// RelativeEncoderLayer. Round 6 (R5 + three independent changes):
//  - gemm_bt: XCD-aware block swizzle (T1). Grid dispatch is x-fastest and
//    round-robins XCDs, so blocks sharing an A-panel landed on 8 different
//    L2s (W2 FETCH 271MB vs 72MB ideal). Remap gives each XCD a contiguous
//    m-slab. Bijective: all grids have nwg % 8 == 0.
//  - attn_flash VALU diet: exp2-folding (qrel pre-scaled by 0.125*log2e ->
//    1 fma + 1 v_exp per score), native bf16 cvt (hardware RNE), rsum via
//    ones-column MFMA instead of 256 scalar adds + shuffle reduce.
//  - ln_res: float4, row kept in registers, LDS buffer removed.
// ---------------------------------------------------------------------------

typedef __bf16 bf16x8 __attribute__((ext_vector_type(8)));
typedef float  f32x4  __attribute__((ext_vector_type(4)));

__device__ __forceinline__ unsigned short f2bf(float f) {
  __bf16 h = (__bf16)f;                       // hardware RNE on gfx950
  union { __bf16 h; unsigned short u; } x; x.h = h;
  return x.u;
}
__device__ __forceinline__ float bf2f(unsigned short h) {
  union { unsigned u; float f; } x; x.u = ((unsigned)h) << 16; return x.f;
}

// Direct async global->LDS, 16B per lane. LDS dest is wave-uniform base +
// lane*16 (HW-fixed pattern); global src is per-lane.
__device__ __forceinline__ void gload_lds16(
    const unsigned short* g,
    __attribute__((address_space(3))) unsigned int* l) {
  __builtin_amdgcn_global_load_lds(
      (const __attribute__((address_space(1))) unsigned int*)g, l, 16, 0, 0);
}

// ---------------------------------------------------------------------------
// GEMM: C[M,N] = A[M,K] @ Bt[N,K]^T + bias, 128x128 tile, BK=32,
// 4 waves of 64x64, global_load_lds staging + XCD-aware block swizzle.
// EPI: 0 = bias->bf16, 1 = bias->f32, 2 = bias+relu->bf16
// ---------------------------------------------------------------------------
template<int EPI>
__global__ __launch_bounds__(256) void gemm_bt(
    const unsigned short* __restrict__ A,
    const unsigned short* __restrict__ Bt,
    const float* __restrict__ bias,
    void* __restrict__ Cout,
    int M, int N, int K)
{
  __shared__ __align__(16) unsigned short As[128 * 32];
  __shared__ __align__(16) unsigned short Bs[128 * 32];
  const int tid = threadIdx.x;
  const int lane = tid & 63, wv = tid >> 6;
  const int lq = lane >> 4, lm = lane & 15;
  const int wr = wv >> 1, wc = wv & 1;

  // XCD-aware swizzle: dispatch id = y*nx + x round-robins XCDs (id % 8).
  // Remap so XCD c owns a contiguous chunk of tile space (nwg % 8 == 0).
  const int nx = gridDim.x;
  const int nwg = nx * gridDim.y;
  int bid = blockIdx.y * nx + blockIdx.x;
  bid = (bid & 7) * (nwg >> 3) + (bid >> 3);
  const int m0 = (bid / nx) * 128, n0 = (bid % nx) * 128;

  const unsigned short* ga0 = A  + (size_t)(m0 + (tid >> 2)) * K + (tid & 3) * 8;
  const unsigned short* gb0 = Bt + (size_t)(n0 + (tid >> 2)) * K + (tid & 3) * 8;
  const size_t rstep = (size_t)64 * K;

  // Wave-uniform LDS staging bases: wave wv writes rows wv*16..wv*16+15
  // (1 KiB = 256 uints); +1024 uints = +4096 B = rows 64+.
  __attribute__((address_space(3))) unsigned int* lA =
      (__attribute__((address_space(3))) unsigned int*)As + wv * 256;
  __attribute__((address_space(3))) unsigned int* lB =
      (__attribute__((address_space(3))) unsigned int*)Bs + wv * 256;

  const char* fa = (const char*)As + (wr * 64 + lm) * 64 + lq * 16;
  const char* fb = (const char*)Bs + (wc * 64 + lm) * 64 + lq * 16;

  f32x4 acc[4][4] = {};
  const int nk = K >> 5;
  for (int kt = 0; kt < nk; ++kt) {
    __syncthreads();                 // all waves done reading previous tile
    gload_lds16(ga0,         lA);
    gload_lds16(ga0 + rstep, lA + 1024);
    gload_lds16(gb0,         lB);
    gload_lds16(gb0 + rstep, lB + 1024);
    ga0 += 32; gb0 += 32;
    __syncthreads();                 // compiler drains vmcnt before barrier
    bf16x8 af[4], bfr[4];
    #pragma unroll
    for (int i = 0; i < 4; ++i) af[i]  = *(const bf16x8*)(fa + i * 16 * 64);
    #pragma unroll
    for (int j = 0; j < 4; ++j) bfr[j] = *(const bf16x8*)(fb + j * 16 * 64);
    #pragma unroll
    for (int i = 0; i < 4; ++i)
      #pragma unroll
      for (int j = 0; j < 4; ++j)
        acc[i][j] = __builtin_amdgcn_mfma_f32_16x16x32_bf16(af[i], bfr[j], acc[i][j], 0, 0, 0);
  }
  #pragma unroll
  for (int i = 0; i < 4; ++i) {
    #pragma unroll
    for (int j = 0; j < 4; ++j) {
      const int col = n0 + wc * 64 + j * 16 + lm;
      const float bv = bias[col];
      #pragma unroll
      for (int r = 0; r < 4; ++r) {
        const int row = m0 + wr * 64 + i * 16 + lq * 4 + r;
        float v = acc[i][j][r] + bv;
        if (EPI == 2) v = fmaxf(v, 0.0f);
        if (EPI == 1) ((float*)Cout)[(size_t)row * N + col] = v;
        else ((unsigned short*)Cout)[(size_t)row * N + col] = f2bf(v);
      }
    }
  }
}

// ---------------------------------------------------------------------------
// Transpose-cast: out[C][R] bf16 = in[R][C] fp32.  32x32 LDS tiles.
// ---------------------------------------------------------------------------
__global__ __launch_bounds__(256) void tcast(
    const float* __restrict__ in, unsigned short* __restrict__ out, int R, int C)
{
  __shared__ float tile[32][33];
  const int tx = threadIdx.x & 31, ty = threadIdx.x >> 5;
  const int r0 = blockIdx.y * 32, c0 = blockIdx.x * 32;
  #pragma unroll
  for (int s = 0; s < 4; ++s)
    tile[ty + s * 8][tx] = in[(size_t)(r0 + ty + s * 8) * C + c0 + tx];
  __syncthreads();
  #pragma unroll
  for (int s = 0; s < 4; ++s)
    out[(size_t)(c0 + ty + s * 8) * R + r0 + tx] = f2bf(tile[tx][ty + s * 8]);
}

__global__ __launch_bounds__(256) void cast4(
    const float* __restrict__ in, unsigned short* __restrict__ out, int n)
{
  int i = (blockIdx.x * 256 + threadIdx.x) * 4;
  if (i < n) {
    float4 v = *(const float4*)(in + i);
    ushort4 o;
    o.x = f2bf(v.x); o.y = f2bf(v.y); o.z = f2bf(v.z); o.w = f2bf(v.w);
    *(ushort4*)(out + i) = o;
  }
}

// ---------------------------------------------------------------------------
// V-transpose: VP[8192 tok][1024] bf16 -> VPT[h][d][b][1024 pos] bf16.
// ---------------------------------------------------------------------------
__global__ __launch_bounds__(256) void vtrans(
    const unsigned short* __restrict__ VP, unsigned short* __restrict__ VPT)
{
  __shared__ unsigned short tile[64 * 66];
  const int pt = blockIdx.x, h = blockIdx.y, b = blockIdx.z;
  const int tid = threadIdx.x;
  const int p = tid >> 2, c0 = (tid & 3) * 16;
  const unsigned short* src = VP + (size_t)(b * 1024 + pt * 64 + p) * 1024 + h * 64 + c0;
  union { uint4 q; unsigned int u[4]; } t0, t1;
  t0.q = *(const uint4*)src;
  t1.q = *(const uint4*)(src + 8);
  #pragma unroll
  for (int e = 0; e < 4; ++e) {
    *(unsigned int*)&tile[p * 66 + c0 + e * 2]     = t0.u[e];
    *(unsigned int*)&tile[p * 66 + c0 + 8 + e * 2] = t1.u[e];
  }
  __syncthreads();
  const int d = tid >> 2, p0 = (tid & 3) * 16;
  union { uint4 q[2]; unsigned short s[16]; } ob;
  #pragma unroll
  for (int e = 0; e < 16; ++e) ob.s[e] = tile[(p0 + e) * 66 + d];
  unsigned short* dst = VPT + ((size_t)(h * 64 + d) * 8 + b) * 1024 + pt * 64 + p0;
  *(uint4*)dst       = ob.q[0];
  *(uint4*)(dst + 8) = ob.q[1];
}

// ---------------------------------------------------------------------------
// Flash attention with Shaw rel-pos, no-max softmax (|s| < ~2.5 -> exp safe,
// math-identical to softmax).  64 Q-rows/block, 64-wide K tiles, 16 rows/wave.
// Qrel computed in-kernel (6 MFMAs), PRE-SCALED by 0.125*log2(e) so the
// softmax inner loop is one fma + one v_exp per score.  P cast to bf16 via
// hardware RNE.  Row-sum (softmax denominator) comes free from a ones-column
// MFMA on the same P fragments used for P.V — consistent bf16 numerics.
// ---------------------------------------------------------------------------
__global__ __launch_bounds__(256, 3) void attn_flash(
    const unsigned short* __restrict__ Qp,
    const unsigned short* __restrict__ Kp,
    const unsigned short* __restrict__ VPT,
    const float* __restrict__ relk,
    const float* __restrict__ relv,
    unsigned short* __restrict__ ctx)
{
  const int qt = blockIdx.x, h = blockIdx.y, b = blockIdx.z;
  const int tid = threadIdx.x;
  const int lane = tid & 63, wv = tid >> 6;
  const int lq = lane >> 4, lm = lane & 15;

  __shared__ __align__(16) unsigned short Kt[64][72];   // [pos][d]
  __shared__ __align__(16) unsigned short Vt[64][72];   // [d][pos]
  __shared__ __align__(16) unsigned short Pt[64][72];   // [qrow][pos] / RaccB
  __shared__ __align__(16) unsigned short relvT[64][32];// [d][bin 0..31] bf16
  __shared__ float qrel_s[64][33];                      // pre-scaled by CE
  __shared__ float Racc[64][33];

  const float CE = 0.125f * 1.44269504088896340736f;    // 1/sqrt(64) * log2(e)

  const int tok0 = b * 1024 + qt * 64;

  for (int i = tid; i < 64 * 33; i += 256) {
    const int rr = i / 33, ss = i - rr * 33;
    Racc[rr][ss] = 0.0f;
  }
  for (int i = tid; i < 64 * 32; i += 256) {
    const int dd = i >> 5, ss = i & 31;
    relvT[dd][ss] = f2bf(relv[ss * 64 + dd]);
  }

  // Q fragments (A-layout): rows wv*16+lm, d = {lq*8.., 32+lq*8..}
  bf16x8 qf0, qf1;
  {
    const unsigned short* qg = Qp + (size_t)(tok0 + wv * 16 + lm) * 1024 + h * 64;
    qf0 = *(const bf16x8*)(qg + lq * 8);
    qf1 = *(const bf16x8*)(qg + 32 + lq * 8);
  }

  // Srel = Q @ rel_k^T  (bins 0..32; tiles of 16 bins, zero-padded),
  // stored PRE-SCALED by CE so downstream is exp2(fma(S, CE, qrel)).
  #pragma unroll
  for (int t = 0; t < 3; ++t) {
    const int bin = t * 16 + lm;
    union { bf16x8 v; unsigned short s[8]; } rk0, rk1;
    #pragma unroll
    for (int e = 0; e < 8; ++e) { rk0.s[e] = 0; rk1.s[e] = 0; }
    if (bin < 33) {
      const float* rp = relk + bin * 64 + lq * 8;
      #pragma unroll
      for (int e = 0; e < 8; ++e) {
        rk0.s[e] = f2bf(rp[e]);
        rk1.s[e] = f2bf(rp[32 + e]);
      }
    }
    f32x4 Sr = {};
    Sr = __builtin_amdgcn_mfma_f32_16x16x32_bf16(qf0, rk0.v, Sr, 0, 0, 0);
    Sr = __builtin_amdgcn_mfma_f32_16x16x32_bf16(qf1, rk1.v, Sr, 0, 0, 0);
    if (bin < 33) {
      #pragma unroll
      for (int r = 0; r < 4; ++r) qrel_s[wv * 16 + lq * 4 + r][bin] = Sr[r] * CE;
    }
  }
  __syncthreads();

  float q0a[4], q32a[4];
  #pragma unroll
  for (int r = 0; r < 4; ++r) {
    const int rowl = wv * 16 + lq * 4 + r;
    q0a[r]  = qrel_s[rowl][0];
    q32a[r] = qrel_s[rowl][32];
  }

  union { bf16x8 v; unsigned short s[8]; } one8;
  #pragma unroll
  for (int e = 0; e < 8; ++e) one8.s[e] = 0x3F80;       // bf16 1.0

  f32x4 Oa[4] = {};
  f32x4 Rs = {};                                        // row-sum accumulator
  float r0a[4] = {0, 0, 0, 0}, r32a[4] = {0, 0, 0, 0};

  const int srow = tid >> 2, scol = (tid & 3) * 16;
  const unsigned short* kg = Kp + (size_t)(b * 1024 + srow) * 1024 + h * 64 + scol;
  const unsigned short* vg = VPT + ((size_t)(h * 64 + srow) * 8 + b) * 1024 + scol;
  const int qa0 = qt * 64 + wv * 16;          // first absolute q-row of this wave

  for (int kt = 0; kt < 16; ++kt) {
    __syncthreads();
    *(uint4*)&Kt[srow][scol]     = *(const uint4*)(kg);
    *(uint4*)&Kt[srow][scol + 8] = *(const uint4*)(kg + 8);
    *(uint4*)&Vt[srow][scol]     = *(const uint4*)(vg);
    *(uint4*)&Vt[srow][scol + 8] = *(const uint4*)(vg + 8);
    kg += 64 * 1024;
    vg += 64;
    __syncthreads();

    #pragma unroll
    for (int tj = 0; tj < 4; ++tj) {
      bf16x8 kf0 = *(const bf16x8*)(&Kt[tj * 16 + lm][lq * 8]);
      bf16x8 kf1 = *(const bf16x8*)(&Kt[tj * 16 + lm][32 + lq * 8]);
      f32x4 S = {};
      S = __builtin_amdgcn_mfma_f32_16x16x32_bf16(qf0, kf0, S, 0, 0, 0);
      S = __builtin_amdgcn_mfma_f32_16x16x32_bf16(qf1, kf1, S, 0, 0, 0);
      const int c0 = kt * 64 + tj * 16;
      if (c0 + 31 <= qa0) {
        #pragma unroll
        for (int r = 0; r < 4; ++r) {
          const float p = __builtin_amdgcn_exp2f(fmaf(S[r], CE, q0a[r]));
          r0a[r] += p;
          Pt[wv * 16 + lq * 4 + r][tj * 16 + lm] = f2bf(p);
        }
      } else if (c0 >= qa0 + 31) {
        #pragma unroll
        for (int r = 0; r < 4; ++r) {
          const float p = __builtin_amdgcn_exp2f(fmaf(S[r], CE, q32a[r]));
          r32a[r] += p;
          Pt[wv * 16 + lq * 4 + r][tj * 16 + lm] = f2bf(p);
        }
      } else {
        const int kpos = c0 + lm;
        #pragma unroll
        for (int r = 0; r < 4; ++r) {
          const int rowl = wv * 16 + lq * 4 + r;
          const int dist = kpos - (qt * 64 + rowl);
          const int bin = (dist < -16 ? 0 : (dist > 16 ? 32 : dist + 16));
          const float p = __builtin_amdgcn_exp2f(fmaf(S[r], CE, qrel_s[rowl][bin]));
          if (bin == 0)       r0a[r]  += p;
          else if (bin == 32) r32a[r] += p;
          else Racc[rowl][bin] = p;      // each (row,bin 1..31) hit exactly once
          Pt[rowl][tj * 16 + lm] = f2bf(p);
        }
      }
    }
    __syncthreads();   // order ALL P-stores before P.V fragment reads
    const int prow = wv * 16 + lm;
    bf16x8 pf0 = *(const bf16x8*)(&Pt[prow][lq * 8]);
    bf16x8 pf1 = *(const bf16x8*)(&Pt[prow][32 + lq * 8]);
    Rs = __builtin_amdgcn_mfma_f32_16x16x32_bf16(pf0, one8.v, Rs, 0, 0, 0);
    Rs = __builtin_amdgcn_mfma_f32_16x16x32_bf16(pf1, one8.v, Rs, 0, 0, 0);
    #pragma unroll
    for (int dt = 0; dt < 4; ++dt) {
      bf16x8 vf0 = *(const bf16x8*)(&Vt[dt * 16 + lm][lq * 8]);
      bf16x8 vf1 = *(const bf16x8*)(&Vt[dt * 16 + lm][32 + lq * 8]);
      Oa[dt] = __builtin_amdgcn_mfma_f32_16x16x32_bf16(pf0, vf0, Oa[dt], 0, 0, 0);
      Oa[dt] = __builtin_amdgcn_mfma_f32_16x16x32_bf16(pf1, vf1, Oa[dt], 0, 0, 0);
    }
  }

  // reduce per-lane clip-bin partials across the 16 lanes sharing each row
  #pragma unroll
  for (int r = 0; r < 4; ++r) {
    #pragma unroll
    for (int off = 1; off < 16; off <<= 1) {
      r0a[r]  += __shfl_xor(r0a[r],  off, 64);
      r32a[r] += __shfl_xor(r32a[r], off, 64);
    }
  }
  if (lm == 0) {
    #pragma unroll
    for (int r = 0; r < 4; ++r) Racc[wv * 16 + lq * 4 + r][0] = r0a[r];
  }
  __syncthreads();
  for (int i = tid; i < 64 * 32; i += 256) {
    const int rr = i >> 5, cc = i & 31;
    Pt[rr][cc] = f2bf(Racc[rr][cc]);
  }
  __syncthreads();

  bf16x8 raf = *(const bf16x8*)(&Pt[wv * 16 + lm][lq * 8]);
  #pragma unroll
  for (int dt = 0; dt < 4; ++dt) {
    bf16x8 rvb = *(const bf16x8*)(&relvT[dt * 16 + lm][lq * 8]);
    f32x4 O2 = {};
    O2 = __builtin_amdgcn_mfma_f32_16x16x32_bf16(raf, rvb, O2, 0, 0, 0);
    const float rv32 = relv[32 * 64 + dt * 16 + lm];
    #pragma unroll
    for (int r = 0; r < 4; ++r) {
      const int rowl = wv * 16 + lq * 4 + r;
      const float v = (Oa[dt][r] + O2[r] + r32a[r] * rv32) / Rs[r];
      ctx[(size_t)(tok0 + rowl) * 1024 + h * 64 + dt * 16 + lm] = f2bf(v);
    }
  }
}

// ---------------------------------------------------------------------------
// LayerNorm with residual: y = LN(x + res)*g + b -> fp32 (and optional bf16).
// float4 per thread (256 thr x 4 = 1024), row kept in registers, no LDS buf.
// ---------------------------------------------------------------------------
template<bool WB>
__global__ __launch_bounds__(256) void ln_res(
    const float* __restrict__ x, const float* __restrict__ res,
    const float* __restrict__ g, const float* __restrict__ bta,
    float* __restrict__ of, unsigned short* __restrict__ ob)
{
  const int row = blockIdx.x;
  const int tid = threadIdx.x;
  __shared__ float red[8];
  const size_t base = (size_t)row * 1024 + tid * 4;
  const float4 xv = *(const float4*)(x + base);
  const float4 rv = *(const float4*)(res + base);
  float v0 = xv.x + rv.x, v1 = xv.y + rv.y, v2 = xv.z + rv.z, v3 = xv.w + rv.w;
  float s1 = v0 + v1 + v2 + v3;
  float s2 = v0 * v0 + v1 * v1 + v2 * v2 + v3 * v3;
  #pragma unroll
  for (int off = 1; off < 64; off <<= 1) {
    s1 += __shfl_xor(s1, off, 64);
    s2 += __shfl_xor(s2, off, 64);
  }
  const int wv = tid >> 6;
  if ((tid & 63) == 0) { red[wv * 2] = s1; red[wv * 2 + 1] = s2; }
  __syncthreads();
  s1 = red[0] + red[2] + red[4] + red[6];
  s2 = red[1] + red[3] + red[5] + red[7];
  const float mean = s1 * (1.f / 1024.f);
  const float var = s2 * (1.f / 1024.f) - mean * mean;
  const float rstd = rsqrtf(var + 1e-6f);
  const float4 gv = *(const float4*)(g + tid * 4);
  const float4 bv = *(const float4*)(bta + tid * 4);
  float y0 = (v0 - mean) * rstd * gv.x + bv.x;
  float y1 = (v1 - mean) * rstd * gv.y + bv.y;
  float y2 = (v2 - mean) * rstd * gv.z + bv.z;
  float y3 = (v3 - mean) * rstd * gv.w + bv.w;
  float4 yo; yo.x = y0; yo.y = y1; yo.z = y2; yo.w = y3;
  *(float4*)(of + base) = yo;
  if (WB) {
    ushort4 o;
    o.x = f2bf(y0); o.y = f2bf(y1); o.z = f2bf(y2); o.w = f2bf(y3);
    *(ushort4*)(ob + base) = o;
  }
}

// ---------------------------------------------------------------------------
extern "C" void kernel_launch(void* const* d_in, const int* in_sizes, int n_in,
                              void* d_out, int out_size, void* d_ws, size_t ws_size,
                              hipStream_t stream) {
  (void)in_sizes; (void)n_in; (void)out_size; (void)ws_size;
  const float* q    = (const float*)d_in[0];
  const float* k    = (const float*)d_in[1];
  const float* v    = (const float*)d_in[2];
  const float* wq   = (const float*)d_in[3];
  const float* bq   = (const float*)d_in[4];
  const float* wk   = (const float*)d_in[5];
  const float* bk   = (const float*)d_in[6];
  const float* wv_  = (const float*)d_in[7];
  const float* bv   = (const float*)d_in[8];
  const float* wfc  = (const float*)d_in[9];
  const float* bfc  = (const float*)d_in[10];
  const float* w1   = (const float*)d_in[11];
  const float* b1   = (const float*)d_in[12];
  const float* w2   = (const float*)d_in[13];
  const float* b2   = (const float*)d_in[14];
  const float* ln_g = (const float*)d_in[15];
  const float* ln_b = (const float*)d_in[16];
  const float* rel_k = (const float*)d_in[17];
  const float* rel_v = (const float*)d_in[18];

  char* ws = (char*)d_ws;
  const size_t MB = 1ull << 20;
  unsigned short* WQT  = (unsigned short*)(ws + 0 * MB);
  unsigned short* WKT  = (unsigned short*)(ws + 2 * MB);
  unsigned short* WVT  = (unsigned short*)(ws + 4 * MB);
  unsigned short* WFCT = (unsigned short*)(ws + 6 * MB);
  unsigned short* W1T  = (unsigned short*)(ws + 8 * MB);    // [4096][1024]
  unsigned short* W2T  = (unsigned short*)(ws + 16 * MB);   // [1024][4096]
  unsigned short* QP   = (unsigned short*)(ws + 24 * MB);   // [24,40)
  unsigned short* KP   = (unsigned short*)(ws + 40 * MB);   // [40,56)
  unsigned short* VP   = (unsigned short*)(ws + 56 * MB);   // [56,72)
  unsigned short* QBF  = (unsigned short*)(ws + 72 * MB);   // [72,88)
  unsigned short* KBF  = (unsigned short*)(ws + 88 * MB);   // [88,104)
  unsigned short* VBF  = (unsigned short*)(ws + 104 * MB);  // [104,120)
  // lifetime reuse (all producers strictly after the region's last reader):
  unsigned short* VPT  = QBF;                               // [72,88)
  unsigned short* CTX  = KBF;                               // [88,104)
  float*          OTMP = (float*)(ws + 104 * MB);           // [104,136)
  float*          X1F  = (float*)(ws + 24 * MB);            // [24,56)
  unsigned short* X1BF = VP;                                // [56,72)
  unsigned short* HBUF = (unsigned short*)(ws + 72 * MB);   // [72,136)
  float*          Y2   = (float*)(ws + 136 * MB);           // [136,168)

  const dim3 blk(256);
  const int NTOK = 8192;

  tcast<<<dim3(32, 32), blk, 0, stream>>>(wq, WQT, 1024, 1024);
  tcast<<<dim3(32, 32), blk, 0, stream>>>(wk, WKT, 1024, 1024);
  tcast<<<dim3(32, 32), blk, 0, stream>>>(wv_, WVT, 1024, 1024);
  tcast<<<dim3(32, 32), blk, 0, stream>>>(wfc, WFCT, 1024, 1024);
  tcast<<<dim3(128, 32), blk, 0, stream>>>(w1, W1T, 1024, 4096);
  tcast<<<dim3(32, 128), blk, 0, stream>>>(w2, W2T, 4096, 1024);
  cast4<<<8192, blk, 0, stream>>>(q, QBF, NTOK * 1024);
  cast4<<<8192, blk, 0, stream>>>(k, KBF, NTOK * 1024);
  cast4<<<8192, blk, 0, stream>>>(v, VBF, NTOK * 1024);

  gemm_bt<0><<<dim3(8, 64), blk, 0, stream>>>(QBF, WQT, bq, QP, NTOK, 1024, 1024);
  gemm_bt<0><<<dim3(8, 64), blk, 0, stream>>>(KBF, WKT, bk, KP, NTOK, 1024, 1024);
  gemm_bt<0><<<dim3(8, 64), blk, 0, stream>>>(VBF, WVT, bv, VP, NTOK, 1024, 1024);

  vtrans<<<dim3(16, 16, 8), blk, 0, stream>>>(VP, VPT);

  attn_flash<<<dim3(16, 16, 8), blk, 0, stream>>>(QP, KP, VPT, rel_k, rel_v, CTX);

  gemm_bt<1><<<dim3(8, 64), blk, 0, stream>>>(CTX, WFCT, bfc, OTMP, NTOK, 1024, 1024);
  ln_res<true><<<8192, blk, 0, stream>>>(OTMP, q, ln_g, ln_b, X1F, X1BF);
  gemm_bt<2><<<dim3(32, 64), blk, 0, stream>>>(X1BF, W1T, b1, HBUF, NTOK, 4096, 1024);
  gemm_bt<1><<<dim3(8, 64), blk, 0, stream>>>(HBUF, W2T, b2, Y2, NTOK, 1024, 4096);
  ln_res<false><<<8192, blk, 0, stream>>>(Y2, X1F, ln_g, ln_b, (float*)d_out, nullptr);
}

// Round 3
// 647.174 us; speedup vs baseline: 1.0645x; 1.0196x over previous
//
#include <hip/hip_runtime.h>
#include <stdint.h>

// ---------------------------------------------------------------------------
// RelativeEncoderLayer. Round 7 (R6 + three attn changes):
//  - attn XCD swizzle: flattened-id remap so each XCD owns one batch b ->
//    K/V panels (4MB/batch) stay in one XCD's L2. FETCH was 139.8MB vs 48
//    ideal (consecutive qt-blocks sharing a K/V panel were round-robined
//    across 8 XCDs).
//  - attn Pt physical-row permute (w*16+lq*4+r -> w*16+r*4+lq): kills the
//    4-way bank conflict on per-score scalar P stores (1.01e7 conflict
//    cycles/dispatch = 14% of kernel time). Reads remap lm bijectively.
//  - attn T14 async staging: K/V tile kt+1 prefetched into registers during
//    kt's compute; only ds_writes remain between barriers (latency hidden).
//  - gemm/tcast/cast4/vtrans/ln_res: unchanged from R6.
// ---------------------------------------------------------------------------

typedef __bf16 bf16x8 __attribute__((ext_vector_type(8)));
typedef float  f32x4  __attribute__((ext_vector_type(4)));

__device__ __forceinline__ unsigned short f2bf(float f) {
  __bf16 h = (__bf16)f;                       // hardware RNE on gfx950
  union { __bf16 h; unsigned short u; } x; x.h = h;
  return x.u;
}
__device__ __forceinline__ float bf2f(unsigned short h) {
  union { unsigned u; float f; } x; x.u = ((unsigned)h) << 16; return x.f;
}

// Direct async global->LDS, 16B per lane. LDS dest is wave-uniform base +
// lane*16 (HW-fixed pattern); global src is per-lane.
__device__ __forceinline__ void gload_lds16(
    const unsigned short* g,
    __attribute__((address_space(3))) unsigned int* l) {
  __builtin_amdgcn_global_load_lds(
      (const __attribute__((address_space(1))) unsigned int*)g, l, 16, 0, 0);
}

// ---------------------------------------------------------------------------
// GEMM: C[M,N] = A[M,K] @ Bt[N,K]^T + bias, 128x128 tile, BK=32,
// 4 waves of 64x64, global_load_lds staging + XCD-aware block swizzle.
// EPI: 0 = bias->bf16, 1 = bias->f32, 2 = bias+relu->bf16
// ---------------------------------------------------------------------------
template<int EPI>
__global__ __launch_bounds__(256) void gemm_bt(
    const unsigned short* __restrict__ A,
    const unsigned short* __restrict__ Bt,
    const float* __restrict__ bias,
    void* __restrict__ Cout,
    int M, int N, int K)
{
  __shared__ __align__(16) unsigned short As[128 * 32];
  __shared__ __align__(16) unsigned short Bs[128 * 32];
  const int tid = threadIdx.x;
  const int lane = tid & 63, wv = tid >> 6;
  const int lq = lane >> 4, lm = lane & 15;
  const int wr = wv >> 1, wc = wv & 1;

  // XCD-aware swizzle: dispatch id = y*nx + x round-robins XCDs (id % 8).
  // Remap so XCD c owns a contiguous chunk of tile space (nwg % 8 == 0).
  const int nx = gridDim.x;
  const int nwg = nx * gridDim.y;
  int bid = blockIdx.y * nx + blockIdx.x;
  bid = (bid & 7) * (nwg >> 3) + (bid >> 3);
  const int m0 = (bid / nx) * 128, n0 = (bid % nx) * 128;

  const unsigned short* ga0 = A  + (size_t)(m0 + (tid >> 2)) * K + (tid & 3) * 8;
  const unsigned short* gb0 = Bt + (size_t)(n0 + (tid >> 2)) * K + (tid & 3) * 8;
  const size_t rstep = (size_t)64 * K;

  // Wave-uniform LDS staging bases: wave wv writes rows wv*16..wv*16+15
  // (1 KiB = 256 uints); +1024 uints = +4096 B = rows 64+.
  __attribute__((address_space(3))) unsigned int* lA =
      (__attribute__((address_space(3))) unsigned int*)As + wv * 256;
  __attribute__((address_space(3))) unsigned int* lB =
      (__attribute__((address_space(3))) unsigned int*)Bs + wv * 256;

  const char* fa = (const char*)As + (wr * 64 + lm) * 64 + lq * 16;
  const char* fb = (const char*)Bs + (wc * 64 + lm) * 64 + lq * 16;

  f32x4 acc[4][4] = {};
  const int nk = K >> 5;
  for (int kt = 0; kt < nk; ++kt) {
    __syncthreads();                 // all waves done reading previous tile
    gload_lds16(ga0,         lA);
    gload_lds16(ga0 + rstep, lA + 1024);
    gload_lds16(gb0,         lB);
    gload_lds16(gb0 + rstep, lB + 1024);
    ga0 += 32; gb0 += 32;
    __syncthreads();                 // compiler drains vmcnt before barrier
    bf16x8 af[4], bfr[4];
    #pragma unroll
    for (int i = 0; i < 4; ++i) af[i]  = *(const bf16x8*)(fa + i * 16 * 64);
    #pragma unroll
    for (int j = 0; j < 4; ++j) bfr[j] = *(const bf16x8*)(fb + j * 16 * 64);
    #pragma unroll
    for (int i = 0; i < 4; ++i)
      #pragma unroll
      for (int j = 0; j < 4; ++j)
        acc[i][j] = __builtin_amdgcn_mfma_f32_16x16x32_bf16(af[i], bfr[j], acc[i][j], 0, 0, 0);
  }
  #pragma unroll
  for (int i = 0; i < 4; ++i) {
    #pragma unroll
    for (int j = 0; j < 4; ++j) {
      const int col = n0 + wc * 64 + j * 16 + lm;
      const float bv = bias[col];
      #pragma unroll
      for (int r = 0; r < 4; ++r) {
        const int row = m0 + wr * 64 + i * 16 + lq * 4 + r;
        float v = acc[i][j][r] + bv;
        if (EPI == 2) v = fmaxf(v, 0.0f);
        if (EPI == 1) ((float*)Cout)[(size_t)row * N + col] = v;
        else ((unsigned short*)Cout)[(size_t)row * N + col] = f2bf(v);
      }
    }
  }
}

// ---------------------------------------------------------------------------
// Transpose-cast: out[C][R] bf16 = in[R][C] fp32.  32x32 LDS tiles.
// ---------------------------------------------------------------------------
__global__ __launch_bounds__(256) void tcast(
    const float* __restrict__ in, unsigned short* __restrict__ out, int R, int C)
{
  __shared__ float tile[32][33];
  const int tx = threadIdx.x & 31, ty = threadIdx.x >> 5;
  const int r0 = blockIdx.y * 32, c0 = blockIdx.x * 32;
  #pragma unroll
  for (int s = 0; s < 4; ++s)
    tile[ty + s * 8][tx] = in[(size_t)(r0 + ty + s * 8) * C + c0 + tx];
  __syncthreads();
  #pragma unroll
  for (int s = 0; s < 4; ++s)
    out[(size_t)(c0 + ty + s * 8) * R + r0 + tx] = f2bf(tile[tx][ty + s * 8]);
}

__global__ __launch_bounds__(256) void cast4(
    const float* __restrict__ in, unsigned short* __restrict__ out, int n)
{
  int i = (blockIdx.x * 256 + threadIdx.x) * 4;
  if (i < n) {
    float4 v = *(const float4*)(in + i);
    ushort4 o;
    o.x = f2bf(v.x); o.y = f2bf(v.y); o.z = f2bf(v.z); o.w = f2bf(v.w);
    *(ushort4*)(out + i) = o;
  }
}

// ---------------------------------------------------------------------------
// V-transpose: VP[8192 tok][1024] bf16 -> VPT[h][d][b][1024 pos] bf16.
// ---------------------------------------------------------------------------
__global__ __launch_bounds__(256) void vtrans(
    const unsigned short* __restrict__ VP, unsigned short* __restrict__ VPT)
{
  __shared__ unsigned short tile[64 * 66];
  const int pt = blockIdx.x, h = blockIdx.y, b = blockIdx.z;
  const int tid = threadIdx.x;
  const int p = tid >> 2, c0 = (tid & 3) * 16;
  const unsigned short* src = VP + (size_t)(b * 1024 + pt * 64 + p) * 1024 + h * 64 + c0;
  union { uint4 q; unsigned int u[4]; } t0, t1;
  t0.q = *(const uint4*)src;
  t1.q = *(const uint4*)(src + 8);
  #pragma unroll
  for (int e = 0; e < 4; ++e) {
    *(unsigned int*)&tile[p * 66 + c0 + e * 2]     = t0.u[e];
    *(unsigned int*)&tile[p * 66 + c0 + 8 + e * 2] = t1.u[e];
  }
  __syncthreads();
  const int d = tid >> 2, p0 = (tid & 3) * 16;
  union { uint4 q[2]; unsigned short s[16]; } ob;
  #pragma unroll
  for (int e = 0; e < 16; ++e) ob.s[e] = tile[(p0 + e) * 66 + d];
  unsigned short* dst = VPT + ((size_t)(h * 64 + d) * 8 + b) * 1024 + pt * 64 + p0;
  *(uint4*)dst       = ob.q[0];
  *(uint4*)(dst + 8) = ob.q[1];
}

// ---------------------------------------------------------------------------
// Flash attention with Shaw rel-pos, no-max softmax (|s| < ~2.5 -> exp safe,
// math-identical to softmax).  64 Q-rows/block, 64-wide K tiles, 16 rows/wave.
// P-tile stored with physical row = w*16 + r*4 + lq (lq/r fields swapped):
// scalar P stores then spread quadrants over distinct banks (was 4-way
// conflict); fragment reads remap lm -> ((lm&3)<<2)|(lm>>2), a bijection of
// the same 16-row block (uniformity and 16B alignment preserved).
// K/V staged via T14 split: next tile prefetched into registers during
// current tile's compute.  XCD swizzle: each XCD owns one batch b.
// ---------------------------------------------------------------------------
__global__ __launch_bounds__(256, 3) void attn_flash(
    const unsigned short* __restrict__ Qp,
    const unsigned short* __restrict__ Kp,
    const unsigned short* __restrict__ VPT,
    const float* __restrict__ relk,
    const float* __restrict__ relv,
    unsigned short* __restrict__ ctx)
{
  // XCD swizzle: hw dispatch id round-robins XCDs (id%8). Remap so XCD c
  // gets work ids [c*256, (c+1)*256) = all of batch b=c (16h x 16qt);
  // K/V panels for one batch = 4MB = one XCD L2. Bijective (2048 = 8*256).
  int id = (blockIdx.z * gridDim.y + blockIdx.y) * gridDim.x + blockIdx.x;
  id = (id & 7) * 256 + (id >> 3);
  const int qt = id & 15, h = (id >> 4) & 15, b = id >> 8;

  const int tid = threadIdx.x;
  const int lane = tid & 63, wv = tid >> 6;
  const int lq = lane >> 4, lm = lane & 15;

  __shared__ __align__(16) unsigned short Kt[64][72];   // [pos][d]
  __shared__ __align__(16) unsigned short Vt[64][72];   // [d][pos]
  __shared__ __align__(16) unsigned short Pt[64][72];   // [qrow(perm)][pos]
  __shared__ __align__(16) unsigned short relvT[64][32];// [d][bin 0..31] bf16
  __shared__ float qrel_s[64][33];                      // pre-scaled by CE
  __shared__ float Racc[64][33];

  const float CE = 0.125f * 1.44269504088896340736f;    // 1/sqrt(64) * log2(e)

  const int tok0 = b * 1024 + qt * 64;

  for (int i = tid; i < 64 * 33; i += 256) {
    const int rr = i / 33, ss = i - rr * 33;
    Racc[rr][ss] = 0.0f;
  }
  for (int i = tid; i < 64 * 32; i += 256) {
    const int dd = i >> 5, ss = i & 31;
    relvT[dd][ss] = f2bf(relv[ss * 64 + dd]);
  }

  // Q fragments (A-layout): rows wv*16+lm, d = {lq*8.., 32+lq*8..}
  bf16x8 qf0, qf1;
  {
    const unsigned short* qg = Qp + (size_t)(tok0 + wv * 16 + lm) * 1024 + h * 64;
    qf0 = *(const bf16x8*)(qg + lq * 8);
    qf1 = *(const bf16x8*)(qg + 32 + lq * 8);
  }

  // Srel = Q @ rel_k^T  (bins 0..32; tiles of 16 bins, zero-padded),
  // stored PRE-SCALED by CE so downstream is exp2(fma(S, CE, qrel)).
  #pragma unroll
  for (int t = 0; t < 3; ++t) {
    const int bin = t * 16 + lm;
    union { bf16x8 v; unsigned short s[8]; } rk0, rk1;
    #pragma unroll
    for (int e = 0; e < 8; ++e) { rk0.s[e] = 0; rk1.s[e] = 0; }
    if (bin < 33) {
      const float* rp = relk + bin * 64 + lq * 8;
      #pragma unroll
      for (int e = 0; e < 8; ++e) {
        rk0.s[e] = f2bf(rp[e]);
        rk1.s[e] = f2bf(rp[32 + e]);
      }
    }
    f32x4 Sr = {};
    Sr = __builtin_amdgcn_mfma_f32_16x16x32_bf16(qf0, rk0.v, Sr, 0, 0, 0);
    Sr = __builtin_amdgcn_mfma_f32_16x16x32_bf16(qf1, rk1.v, Sr, 0, 0, 0);
    if (bin < 33) {
      #pragma unroll
      for (int r = 0; r < 4; ++r) qrel_s[wv * 16 + lq * 4 + r][bin] = Sr[r] * CE;
    }
  }
  __syncthreads();

  float q0a[4], q32a[4];
  #pragma unroll
  for (int r = 0; r < 4; ++r) {
    const int rowl = wv * 16 + lq * 4 + r;
    q0a[r]  = qrel_s[rowl][0];
    q32a[r] = qrel_s[rowl][32];
  }

  union { bf16x8 v; unsigned short s[8]; } one8;
  #pragma unroll
  for (int e = 0; e < 8; ++e) one8.s[e] = 0x3F80;       // bf16 1.0

  f32x4 Oa[4] = {};
  f32x4 Rs = {};                                        // row-sum accumulator
  float r0a[4] = {0, 0, 0, 0}, r32a[4] = {0, 0, 0, 0};

  const int srow = tid >> 2, scol = (tid & 3) * 16;
  const unsigned short* kg = Kp + (size_t)(b * 1024 + srow) * 1024 + h * 64 + scol;
  const unsigned short* vg = VPT + ((size_t)(h * 64 + srow) * 8 + b) * 1024 + scol;
  const int qa0 = qt * 64 + wv * 16;          // first absolute q-row of this wave

  // physical P-row for logical row w*16+lq*4+r  (lq/r fields swapped)
  // store side uses (r*4+lq); read side remaps lm -> ((lm&3)<<2)|(lm>>2).
  const int pread = wv * 16 + ((lm & 3) << 2) + (lm >> 2);

  // T14 prefetch: tile kt=0 into registers now; inside the loop the next
  // tile's loads issue before compute so their latency hides under it.
  uint4 rk0_ = *(const uint4*)(kg);
  uint4 rk1_ = *(const uint4*)(kg + 8);
  uint4 rv0_ = *(const uint4*)(vg);
  uint4 rv1_ = *(const uint4*)(vg + 8);

  for (int kt = 0; kt < 16; ++kt) {
    __syncthreads();                       // prev compute done reading Kt/Vt
    *(uint4*)&Kt[srow][scol]     = rk0_;
    *(uint4*)&Kt[srow][scol + 8] = rk1_;
    *(uint4*)&Vt[srow][scol]     = rv0_;
    *(uint4*)&Vt[srow][scol + 8] = rv1_;
    if (kt < 15) {
      kg += 64 * 1024;
      vg += 64;
      rk0_ = *(const uint4*)(kg);
      rk1_ = *(const uint4*)(kg + 8);
      rv0_ = *(const uint4*)(vg);
      rv1_ = *(const uint4*)(vg + 8);
    }
    __syncthreads();                       // staging visible

    #pragma unroll
    for (int tj = 0; tj < 4; ++tj) {
      bf16x8 kf0 = *(const bf16x8*)(&Kt[tj * 16 + lm][lq * 8]);
      bf16x8 kf1 = *(const bf16x8*)(&Kt[tj * 16 + lm][32 + lq * 8]);
      f32x4 S = {};
      S = __builtin_amdgcn_mfma_f32_16x16x32_bf16(qf0, kf0, S, 0, 0, 0);
      S = __builtin_amdgcn_mfma_f32_16x16x32_bf16(qf1, kf1, S, 0, 0, 0);
      const int c0 = kt * 64 + tj * 16;
      const int prow0 = wv * 16 + lq;      // physical row for r=0; +4 per r
      if (c0 + 31 <= qa0) {
        #pragma unroll
        for (int r = 0; r < 4; ++r) {
          const float p = __builtin_amdgcn_exp2f(fmaf(S[r], CE, q0a[r]));
          r0a[r] += p;
          Pt[prow0 + r * 4][tj * 16 + lm] = f2bf(p);
        }
      } else if (c0 >= qa0 + 31) {
        #pragma unroll
        for (int r = 0; r < 4; ++r) {
          const float p = __builtin_amdgcn_exp2f(fmaf(S[r], CE, q32a[r]));
          r32a[r] += p;
          Pt[prow0 + r * 4][tj * 16 + lm] = f2bf(p);
        }
      } else {
        const int kpos = c0 + lm;
        #pragma unroll
        for (int r = 0; r < 4; ++r) {
          const int rowl = wv * 16 + lq * 4 + r;
          const int dist = kpos - (qt * 64 + rowl);
          const int bin = (dist < -16 ? 0 : (dist > 16 ? 32 : dist + 16));
          const float p = __builtin_amdgcn_exp2f(fmaf(S[r], CE, qrel_s[rowl][bin]));
          if (bin == 0)       r0a[r]  += p;
          else if (bin == 32) r32a[r] += p;
          else Racc[rowl][bin] = p;      // each (row,bin 1..31) hit exactly once
          Pt[prow0 + r * 4][tj * 16 + lm] = f2bf(p);
        }
      }
    }
    __syncthreads();   // order ALL P-stores before P.V fragment reads
    bf16x8 pf0 = *(const bf16x8*)(&Pt[pread][lq * 8]);
    bf16x8 pf1 = *(const bf16x8*)(&Pt[pread][32 + lq * 8]);
    Rs = __builtin_amdgcn_mfma_f32_16x16x32_bf16(pf0, one8.v, Rs, 0, 0, 0);
    Rs = __builtin_amdgcn_mfma_f32_16x16x32_bf16(pf1, one8.v, Rs, 0, 0, 0);
    #pragma unroll
    for (int dt = 0; dt < 4; ++dt) {
      bf16x8 vf0 = *(const bf16x8*)(&Vt[dt * 16 + lm][lq * 8]);
      bf16x8 vf1 = *(const bf16x8*)(&Vt[dt * 16 + lm][32 + lq * 8]);
      Oa[dt] = __builtin_amdgcn_mfma_f32_16x16x32_bf16(pf0, vf0, Oa[dt], 0, 0, 0);
      Oa[dt] = __builtin_amdgcn_mfma_f32_16x16x32_bf16(pf1, vf1, Oa[dt], 0, 0, 0);
    }
  }

  // reduce per-lane clip-bin partials across the 16 lanes sharing each row
  #pragma unroll
  for (int r = 0; r < 4; ++r) {
    #pragma unroll
    for (int off = 1; off < 16; off <<= 1) {
      r0a[r]  += __shfl_xor(r0a[r],  off, 64);
      r32a[r] += __shfl_xor(r32a[r], off, 64);
    }
  }
  if (lm == 0) {
    #pragma unroll
    for (int r = 0; r < 4; ++r) Racc[wv * 16 + lq * 4 + r][0] = r0a[r];
  }
  __syncthreads();
  for (int i = tid; i < 64 * 32; i += 256) {
    const int rr = i >> 5, cc = i & 31;
    Pt[rr][cc] = f2bf(Racc[rr][cc]);
  }
  __syncthreads();

  bf16x8 raf = *(const bf16x8*)(&Pt[wv * 16 + lm][lq * 8]);
  #pragma unroll
  for (int dt = 0; dt < 4; ++dt) {
    bf16x8 rvb = *(const bf16x8*)(&relvT[dt * 16 + lm][lq * 8]);
    f32x4 O2 = {};
    O2 = __builtin_amdgcn_mfma_f32_16x16x32_bf16(raf, rvb, O2, 0, 0, 0);
    const float rv32 = relv[32 * 64 + dt * 16 + lm];
    #pragma unroll
    for (int r = 0; r < 4; ++r) {
      const int rowl = wv * 16 + lq * 4 + r;
      const float v = (Oa[dt][r] + O2[r] + r32a[r] * rv32) / Rs[r];
      ctx[(size_t)(tok0 + rowl) * 1024 + h * 64 + dt * 16 + lm] = f2bf(v);
    }
  }
}

// ---------------------------------------------------------------------------
// LayerNorm with residual: y = LN(x + res)*g + b -> fp32 (and optional bf16).
// float4 per thread (256 thr x 4 = 1024), row kept in registers, no LDS buf.
// ---------------------------------------------------------------------------
template<bool WB>
__global__ __launch_bounds__(256) void ln_res(
    const float* __restrict__ x, const float* __restrict__ res,
    const float* __restrict__ g, const float* __restrict__ bta,
    float* __restrict__ of, unsigned short* __restrict__ ob)
{
  const int row = blockIdx.x;
  const int tid = threadIdx.x;
  __shared__ float red[8];
  const size_t base = (size_t)row * 1024 + tid * 4;
  const float4 xv = *(const float4*)(x + base);
  const float4 rv = *(const float4*)(res + base);
  float v0 = xv.x + rv.x, v1 = xv.y + rv.y, v2 = xv.z + rv.z, v3 = xv.w + rv.w;
  float s1 = v0 + v1 + v2 + v3;
  float s2 = v0 * v0 + v1 * v1 + v2 * v2 + v3 * v3;
  #pragma unroll
  for (int off = 1; off < 64; off <<= 1) {
    s1 += __shfl_xor(s1, off, 64);
    s2 += __shfl_xor(s2, off, 64);
  }
  const int wv = tid >> 6;
  if ((tid & 63) == 0) { red[wv * 2] = s1; red[wv * 2 + 1] = s2; }
  __syncthreads();
  s1 = red[0] + red[2] + red[4] + red[6];
  s2 = red[1] + red[3] + red[5] + red[7];
  const float mean = s1 * (1.f / 1024.f);
  const float var = s2 * (1.f / 1024.f) - mean * mean;
  const float rstd = rsqrtf(var + 1e-6f);
  const float4 gv = *(const float4*)(g + tid * 4);
  const float4 bv = *(const float4*)(bta + tid * 4);
  float y0 = (v0 - mean) * rstd * gv.x + bv.x;
  float y1 = (v1 - mean) * rstd * gv.y + bv.y;
  float y2 = (v2 - mean) * rstd * gv.z + bv.z;
  float y3 = (v3 - mean) * rstd * gv.w + bv.w;
  float4 yo; yo.x = y0; yo.y = y1; yo.z = y2; yo.w = y3;
  *(float4*)(of + base) = yo;
  if (WB) {
    ushort4 o;
    o.x = f2bf(y0); o.y = f2bf(y1); o.z = f2bf(y2); o.w = f2bf(y3);
    *(ushort4*)(ob + base) = o;
  }
}

// ---------------------------------------------------------------------------
extern "C" void kernel_launch(void* const* d_in, const int* in_sizes, int n_in,
                              void* d_out, int out_size, void* d_ws, size_t ws_size,
                              hipStream_t stream) {
  (void)in_sizes; (void)n_in; (void)out_size; (void)ws_size;
  const float* q    = (const float*)d_in[0];
  const float* k    = (const float*)d_in[1];
  const float* v    = (const float*)d_in[2];
  const float* wq   = (const float*)d_in[3];
  const float* bq   = (const float*)d_in[4];
  const float* wk   = (const float*)d_in[5];
  const float* bk   = (const float*)d_in[6];
  const float* wv_  = (const float*)d_in[7];
  const float* bv   = (const float*)d_in[8];
  const float* wfc  = (const float*)d_in[9];
  const float* bfc  = (const float*)d_in[10];
  const float* w1   = (const float*)d_in[11];
  const float* b1   = (const float*)d_in[12];
  const float* w2   = (const float*)d_in[13];
  const float* b2   = (const float*)d_in[14];
  const float* ln_g = (const float*)d_in[15];
  const float* ln_b = (const float*)d_in[16];
  const float* rel_k = (const float*)d_in[17];
  const float* rel_v = (const float*)d_in[18];

  char* ws = (char*)d_ws;
  const size_t MB = 1ull << 20;
  unsigned short* WQT  = (unsigned short*)(ws + 0 * MB);
  unsigned short* WKT  = (unsigned short*)(ws + 2 * MB);
  unsigned short* WVT  = (unsigned short*)(ws + 4 * MB);
  unsigned short* WFCT = (unsigned short*)(ws + 6 * MB);
  unsigned short* W1T  = (unsigned short*)(ws + 8 * MB);    // [4096][1024]
  unsigned short* W2T  = (unsigned short*)(ws + 16 * MB);   // [1024][4096]
  unsigned short* QP   = (unsigned short*)(ws + 24 * MB);   // [24,40)
  unsigned short* KP   = (unsigned short*)(ws + 40 * MB);   // [40,56)
  unsigned short* VP   = (unsigned short*)(ws + 56 * MB);   // [56,72)
  unsigned short* QBF  = (unsigned short*)(ws + 72 * MB);   // [72,88)
  unsigned short* KBF  = (unsigned short*)(ws + 88 * MB);   // [88,104)
  unsigned short* VBF  = (unsigned short*)(ws + 104 * MB);  // [104,120)
  // lifetime reuse (all producers strictly after the region's last reader):
  unsigned short* VPT  = QBF;                               // [72,88)
  unsigned short* CTX  = KBF;                               // [88,104)
  float*          OTMP = (float*)(ws + 104 * MB);           // [104,136)
  float*          X1F  = (float*)(ws + 24 * MB);            // [24,56)
  unsigned short* X1BF = VP;                                // [56,72)
  unsigned short* HBUF = (unsigned short*)(ws + 72 * MB);   // [72,136)
  float*          Y2   = (float*)(ws + 136 * MB);           // [136,168)

  const dim3 blk(256);
  const int NTOK = 8192;

  tcast<<<dim3(32, 32), blk, 0, stream>>>(wq, WQT, 1024, 1024);
  tcast<<<dim3(32, 32), blk, 0, stream>>>(wk, WKT, 1024, 1024);
  tcast<<<dim3(32, 32), blk, 0, stream>>>(wv_, WVT, 1024, 1024);
  tcast<<<dim3(32, 32), blk, 0, stream>>>(wfc, WFCT, 1024, 1024);
  tcast<<<dim3(128, 32), blk, 0, stream>>>(w1, W1T, 1024, 4096);
  tcast<<<dim3(32, 128), blk, 0, stream>>>(w2, W2T, 4096, 1024);
  cast4<<<8192, blk, 0, stream>>>(q, QBF, NTOK * 1024);
  cast4<<<8192, blk, 0, stream>>>(k, KBF, NTOK * 1024);
  cast4<<<8192, blk, 0, stream>>>(v, VBF, NTOK * 1024);

  gemm_bt<0><<<dim3(8, 64), blk, 0, stream>>>(QBF, WQT, bq, QP, NTOK, 1024, 1024);
  gemm_bt<0><<<dim3(8, 64), blk, 0, stream>>>(KBF, WKT, bk, KP, NTOK, 1024, 1024);
  gemm_bt<0><<<dim3(8, 64), blk, 0, stream>>>(VBF, WVT, bv, VP, NTOK, 1024, 1024);

  vtrans<<<dim3(16, 16, 8), blk, 0, stream>>>(VP, VPT);

  attn_flash<<<dim3(16, 16, 8), blk, 0, stream>>>(QP, KP, VPT, rel_k, rel_v, CTX);

  gemm_bt<1><<<dim3(8, 64), blk, 0, stream>>>(CTX, WFCT, bfc, OTMP, NTOK, 1024, 1024);
  ln_res<true><<<8192, blk, 0, stream>>>(OTMP, q, ln_g, ln_b, X1F, X1BF);
  gemm_bt<2><<<dim3(32, 64), blk, 0, stream>>>(X1BF, W1T, b1, HBUF, NTOK, 4096, 1024);
  gemm_bt<1><<<dim3(8, 64), blk, 0, stream>>>(HBUF, W2T, b2, Y2, NTOK, 1024, 4096);
  ln_res<false><<<8192, blk, 0, stream>>>(Y2, X1F, ln_g, ln_b, (float*)d_out, nullptr);
}

// Round 4
// 610.928 us; speedup vs baseline: 1.1276x; 1.0593x over previous
//
#include <hip/hip_runtime.h>
#include <stdint.h>

// ---------------------------------------------------------------------------
// RelativeEncoderLayer. Round 8 (R7 + gemm changes only):
//  - gemm_bt: single-barrier double-buffered 2-phase (catalog T3-minimum):
//    stage tile t+1 into buf^1, compute tile t from buf, ONE vmcnt-draining
//    barrier per K-step.  Loads get the whole compute phase to land before
//    the drain (was: drain exposed ~900cyc HBM latency every K-step at only
//    2 blocks/CU).  LDS 32KB, __launch_bounds__(256,4) pins VGPR<=128.
//  - QKV merged into one grid.z=3 dispatch (stride-uniform A/B/bias/C) ->
//    1536 blocks = 6/CU for that phase.
//  - attn_flash / tcast / cast4 / vtrans / ln_res: unchanged from R7.
// ---------------------------------------------------------------------------

typedef __bf16 bf16x8 __attribute__((ext_vector_type(8)));
typedef float  f32x4  __attribute__((ext_vector_type(4)));

__device__ __forceinline__ unsigned short f2bf(float f) {
  __bf16 h = (__bf16)f;                       // hardware RNE on gfx950
  union { __bf16 h; unsigned short u; } x; x.h = h;
  return x.u;
}
__device__ __forceinline__ float bf2f(unsigned short h) {
  union { unsigned u; float f; } x; x.u = ((unsigned)h) << 16; return x.f;
}

// Direct async global->LDS, 16B per lane. LDS dest is wave-uniform base +
// lane*16 (HW-fixed pattern); global src is per-lane.
__device__ __forceinline__ void gload_lds16(
    const unsigned short* g,
    __attribute__((address_space(3))) unsigned int* l) {
  __builtin_amdgcn_global_load_lds(
      (const __attribute__((address_space(1))) unsigned int*)g, l, 16, 0, 0);
}

// ---------------------------------------------------------------------------
// GEMM: C[M,N] = A[M,K] @ Bt[N,K]^T + bias, 128x128 tile, BK=32,
// 4 waves of 64x64, global_load_lds staging, XCD swizzle, double-buffered
// LDS with one barrier per K-step.  Optional batch via grid.z with element
// strides sA/sB/sC (used for fused QKV; bias picked per z).
// EPI: 0 = bias->bf16, 1 = bias->f32, 2 = bias+relu->bf16
// ---------------------------------------------------------------------------
template<int EPI>
__global__ __launch_bounds__(256, 4) void gemm_bt(
    const unsigned short* __restrict__ A,
    const unsigned short* __restrict__ Bt,
    const float* __restrict__ bias0,
    const float* __restrict__ bias1,
    const float* __restrict__ bias2,
    void* __restrict__ Cout,
    int M, int N, int K,
    size_t sA, size_t sB, size_t sC)
{
  __shared__ __align__(16) unsigned short As[2][128 * 32];
  __shared__ __align__(16) unsigned short Bs[2][128 * 32];
  const int tid = threadIdx.x;
  const int lane = tid & 63, wv = tid >> 6;
  const int lq = lane >> 4, lm = lane & 15;
  const int wr = wv >> 1, wc = wv & 1;

  const int z = blockIdx.z;
  const float* bias = (z == 0) ? bias0 : (z == 1) ? bias1 : bias2;
  A  += (size_t)z * sA;
  Bt += (size_t)z * sB;

  // XCD-aware swizzle within each z-slice: hw id round-robins XCDs (inner
  // dim 8); remap so each XCD owns a contiguous m-chunk (nwg % 8 == 0).
  const int nx = gridDim.x;
  const int nwg = nx * gridDim.y;
  int bid = blockIdx.y * nx + blockIdx.x;
  bid = (bid & 7) * (nwg >> 3) + (bid >> 3);
  const int m0 = (bid / nx) * 128, n0 = (bid % nx) * 128;

  const unsigned short* ga0 = A  + (size_t)(m0 + (tid >> 2)) * K + (tid & 3) * 8;
  const unsigned short* gb0 = Bt + (size_t)(n0 + (tid >> 2)) * K + (tid & 3) * 8;
  const size_t rstep = (size_t)64 * K;

  // Wave-uniform LDS staging bases (buffer stride 2048 dwords = 8192 B).
  __attribute__((address_space(3))) unsigned int* lA =
      (__attribute__((address_space(3))) unsigned int*)As + wv * 256;
  __attribute__((address_space(3))) unsigned int* lB =
      (__attribute__((address_space(3))) unsigned int*)Bs + wv * 256;

  const char* fa = (const char*)As + (wr * 64 + lm) * 64 + lq * 16;
  const char* fb = (const char*)Bs + (wc * 64 + lm) * 64 + lq * 16;

  f32x4 acc[4][4] = {};

  auto compute_tile = [&](int b) {
    bf16x8 af[4], bfr[4];
    #pragma unroll
    for (int i = 0; i < 4; ++i) af[i]  = *(const bf16x8*)(fa + b * 8192 + i * 1024);
    #pragma unroll
    for (int j = 0; j < 4; ++j) bfr[j] = *(const bf16x8*)(fb + b * 8192 + j * 1024);
    #pragma unroll
    for (int i = 0; i < 4; ++i)
      #pragma unroll
      for (int j = 0; j < 4; ++j)
        acc[i][j] = __builtin_amdgcn_mfma_f32_16x16x32_bf16(af[i], bfr[j], acc[i][j], 0, 0, 0);
  };

  const int nk = K >> 5;
  // prologue: stage tile 0 into buf 0
  gload_lds16(ga0,         lA);
  gload_lds16(ga0 + rstep, lA + 1024);
  gload_lds16(gb0,         lB);
  gload_lds16(gb0 + rstep, lB + 1024);
  ga0 += 32; gb0 += 32;
  __syncthreads();                  // drains vmcnt(0): tile 0 visible

  int cur = 0;
  for (int kt = 0; kt < nk - 1; ++kt) {
    const int nb = cur ^ 1;
    // stage tile kt+1 into the other buffer (async, latency hides under MFMA)
    gload_lds16(ga0,         lA + nb * 2048);
    gload_lds16(ga0 + rstep, lA + nb * 2048 + 1024);
    gload_lds16(gb0,         lB + nb * 2048);
    gload_lds16(gb0 + rstep, lB + nb * 2048 + 1024);
    ga0 += 32; gb0 += 32;
    compute_tile(cur);
    __syncthreads();                // drain + barrier: next tile ready; all
    cur = nb;                       // waves done reading old buffer
  }
  compute_tile(cur);

  #pragma unroll
  for (int i = 0; i < 4; ++i) {
    #pragma unroll
    for (int j = 0; j < 4; ++j) {
      const int col = n0 + wc * 64 + j * 16 + lm;
      const float bv = bias[col];
      #pragma unroll
      for (int r = 0; r < 4; ++r) {
        const int row = m0 + wr * 64 + i * 16 + lq * 4 + r;
        float v = acc[i][j][r] + bv;
        if (EPI == 2) v = fmaxf(v, 0.0f);
        if (EPI == 1) ((float*)Cout)[(size_t)row * N + col] = v;
        else ((unsigned short*)Cout + (size_t)z * sC)[(size_t)row * N + col] = f2bf(v);
      }
    }
  }
}

// ---------------------------------------------------------------------------
// Transpose-cast: out[C][R] bf16 = in[R][C] fp32.  32x32 LDS tiles.
// ---------------------------------------------------------------------------
__global__ __launch_bounds__(256) void tcast(
    const float* __restrict__ in, unsigned short* __restrict__ out, int R, int C)
{
  __shared__ float tile[32][33];
  const int tx = threadIdx.x & 31, ty = threadIdx.x >> 5;
  const int r0 = blockIdx.y * 32, c0 = blockIdx.x * 32;
  #pragma unroll
  for (int s = 0; s < 4; ++s)
    tile[ty + s * 8][tx] = in[(size_t)(r0 + ty + s * 8) * C + c0 + tx];
  __syncthreads();
  #pragma unroll
  for (int s = 0; s < 4; ++s)
    out[(size_t)(c0 + ty + s * 8) * R + r0 + tx] = f2bf(tile[tx][ty + s * 8]);
}

__global__ __launch_bounds__(256) void cast4(
    const float* __restrict__ in, unsigned short* __restrict__ out, int n)
{
  int i = (blockIdx.x * 256 + threadIdx.x) * 4;
  if (i < n) {
    float4 v = *(const float4*)(in + i);
    ushort4 o;
    o.x = f2bf(v.x); o.y = f2bf(v.y); o.z = f2bf(v.z); o.w = f2bf(v.w);
    *(ushort4*)(out + i) = o;
  }
}

// ---------------------------------------------------------------------------
// V-transpose: VP[8192 tok][1024] bf16 -> VPT[h][d][b][1024 pos] bf16.
// ---------------------------------------------------------------------------
__global__ __launch_bounds__(256) void vtrans(
    const unsigned short* __restrict__ VP, unsigned short* __restrict__ VPT)
{
  __shared__ unsigned short tile[64 * 66];
  const int pt = blockIdx.x, h = blockIdx.y, b = blockIdx.z;
  const int tid = threadIdx.x;
  const int p = tid >> 2, c0 = (tid & 3) * 16;
  const unsigned short* src = VP + (size_t)(b * 1024 + pt * 64 + p) * 1024 + h * 64 + c0;
  union { uint4 q; unsigned int u[4]; } t0, t1;
  t0.q = *(const uint4*)src;
  t1.q = *(const uint4*)(src + 8);
  #pragma unroll
  for (int e = 0; e < 4; ++e) {
    *(unsigned int*)&tile[p * 66 + c0 + e * 2]     = t0.u[e];
    *(unsigned int*)&tile[p * 66 + c0 + 8 + e * 2] = t1.u[e];
  }
  __syncthreads();
  const int d = tid >> 2, p0 = (tid & 3) * 16;
  union { uint4 q[2]; unsigned short s[16]; } ob;
  #pragma unroll
  for (int e = 0; e < 16; ++e) ob.s[e] = tile[(p0 + e) * 66 + d];
  unsigned short* dst = VPT + ((size_t)(h * 64 + d) * 8 + b) * 1024 + pt * 64 + p0;
  *(uint4*)dst       = ob.q[0];
  *(uint4*)(dst + 8) = ob.q[1];
}

// ---------------------------------------------------------------------------
// Flash attention with Shaw rel-pos, no-max softmax (|s| < ~2.5 -> exp safe,
// math-identical to softmax).  64 Q-rows/block, 64-wide K tiles, 16 rows/wave.
// P-tile stored with physical row = w*16 + r*4 + lq (lq/r fields swapped):
// scalar P stores then spread quadrants over distinct banks (was 4-way
// conflict); fragment reads remap lm -> ((lm&3)<<2)|(lm>>2), a bijection of
// the same 16-row block (uniformity and 16B alignment preserved).
// K/V staged via T14 split: next tile prefetched into registers during
// current tile's compute.  XCD swizzle: each XCD owns one batch b.
// ---------------------------------------------------------------------------
__global__ __launch_bounds__(256, 3) void attn_flash(
    const unsigned short* __restrict__ Qp,
    const unsigned short* __restrict__ Kp,
    const unsigned short* __restrict__ VPT,
    const float* __restrict__ relk,
    const float* __restrict__ relv,
    unsigned short* __restrict__ ctx)
{
  // XCD swizzle: hw dispatch id round-robins XCDs (id%8). Remap so XCD c
  // gets work ids [c*256, (c+1)*256) = all of batch b=c (16h x 16qt);
  // K/V panels for one batch = 4MB = one XCD L2. Bijective (2048 = 8*256).
  int id = (blockIdx.z * gridDim.y + blockIdx.y) * gridDim.x + blockIdx.x;
  id = (id & 7) * 256 + (id >> 3);
  const int qt = id & 15, h = (id >> 4) & 15, b = id >> 8;

  const int tid = threadIdx.x;
  const int lane = tid & 63, wv = tid >> 6;
  const int lq = lane >> 4, lm = lane & 15;

  __shared__ __align__(16) unsigned short Kt[64][72];   // [pos][d]
  __shared__ __align__(16) unsigned short Vt[64][72];   // [d][pos]
  __shared__ __align__(16) unsigned short Pt[64][72];   // [qrow(perm)][pos]
  __shared__ __align__(16) unsigned short relvT[64][32];// [d][bin 0..31] bf16
  __shared__ float qrel_s[64][33];                      // pre-scaled by CE
  __shared__ float Racc[64][33];

  const float CE = 0.125f * 1.44269504088896340736f;    // 1/sqrt(64) * log2(e)

  const int tok0 = b * 1024 + qt * 64;

  for (int i = tid; i < 64 * 33; i += 256) {
    const int rr = i / 33, ss = i - rr * 33;
    Racc[rr][ss] = 0.0f;
  }
  for (int i = tid; i < 64 * 32; i += 256) {
    const int dd = i >> 5, ss = i & 31;
    relvT[dd][ss] = f2bf(relv[ss * 64 + dd]);
  }

  // Q fragments (A-layout): rows wv*16+lm, d = {lq*8.., 32+lq*8..}
  bf16x8 qf0, qf1;
  {
    const unsigned short* qg = Qp + (size_t)(tok0 + wv * 16 + lm) * 1024 + h * 64;
    qf0 = *(const bf16x8*)(qg + lq * 8);
    qf1 = *(const bf16x8*)(qg + 32 + lq * 8);
  }

  // Srel = Q @ rel_k^T  (bins 0..32; tiles of 16 bins, zero-padded),
  // stored PRE-SCALED by CE so downstream is exp2(fma(S, CE, qrel)).
  #pragma unroll
  for (int t = 0; t < 3; ++t) {
    const int bin = t * 16 + lm;
    union { bf16x8 v; unsigned short s[8]; } rk0, rk1;
    #pragma unroll
    for (int e = 0; e < 8; ++e) { rk0.s[e] = 0; rk1.s[e] = 0; }
    if (bin < 33) {
      const float* rp = relk + bin * 64 + lq * 8;
      #pragma unroll
      for (int e = 0; e < 8; ++e) {
        rk0.s[e] = f2bf(rp[e]);
        rk1.s[e] = f2bf(rp[32 + e]);
      }
    }
    f32x4 Sr = {};
    Sr = __builtin_amdgcn_mfma_f32_16x16x32_bf16(qf0, rk0.v, Sr, 0, 0, 0);
    Sr = __builtin_amdgcn_mfma_f32_16x16x32_bf16(qf1, rk1.v, Sr, 0, 0, 0);
    if (bin < 33) {
      #pragma unroll
      for (int r = 0; r < 4; ++r) qrel_s[wv * 16 + lq * 4 + r][bin] = Sr[r] * CE;
    }
  }
  __syncthreads();

  float q0a[4], q32a[4];
  #pragma unroll
  for (int r = 0; r < 4; ++r) {
    const int rowl = wv * 16 + lq * 4 + r;
    q0a[r]  = qrel_s[rowl][0];
    q32a[r] = qrel_s[rowl][32];
  }

  union { bf16x8 v; unsigned short s[8]; } one8;
  #pragma unroll
  for (int e = 0; e < 8; ++e) one8.s[e] = 0x3F80;       // bf16 1.0

  f32x4 Oa[4] = {};
  f32x4 Rs = {};                                        // row-sum accumulator
  float r0a[4] = {0, 0, 0, 0}, r32a[4] = {0, 0, 0, 0};

  const int srow = tid >> 2, scol = (tid & 3) * 16;
  const unsigned short* kg = Kp + (size_t)(b * 1024 + srow) * 1024 + h * 64 + scol;
  const unsigned short* vg = VPT + ((size_t)(h * 64 + srow) * 8 + b) * 1024 + scol;
  const int qa0 = qt * 64 + wv * 16;          // first absolute q-row of this wave

  // physical P-row for logical row w*16+lq*4+r  (lq/r fields swapped)
  // store side uses (r*4+lq); read side remaps lm -> ((lm&3)<<2)|(lm>>2).
  const int pread = wv * 16 + ((lm & 3) << 2) + (lm >> 2);

  // T14 prefetch: tile kt=0 into registers now; inside the loop the next
  // tile's loads issue before compute so their latency hides under it.
  uint4 rk0_ = *(const uint4*)(kg);
  uint4 rk1_ = *(const uint4*)(kg + 8);
  uint4 rv0_ = *(const uint4*)(vg);
  uint4 rv1_ = *(const uint4*)(vg + 8);

  for (int kt = 0; kt < 16; ++kt) {
    __syncthreads();                       // prev compute done reading Kt/Vt
    *(uint4*)&Kt[srow][scol]     = rk0_;
    *(uint4*)&Kt[srow][scol + 8] = rk1_;
    *(uint4*)&Vt[srow][scol]     = rv0_;
    *(uint4*)&Vt[srow][scol + 8] = rv1_;
    if (kt < 15) {
      kg += 64 * 1024;
      vg += 64;
      rk0_ = *(const uint4*)(kg);
      rk1_ = *(const uint4*)(kg + 8);
      rv0_ = *(const uint4*)(vg);
      rv1_ = *(const uint4*)(vg + 8);
    }
    __syncthreads();                       // staging visible

    #pragma unroll
    for (int tj = 0; tj < 4; ++tj) {
      bf16x8 kf0 = *(const bf16x8*)(&Kt[tj * 16 + lm][lq * 8]);
      bf16x8 kf1 = *(const bf16x8*)(&Kt[tj * 16 + lm][32 + lq * 8]);
      f32x4 S = {};
      S = __builtin_amdgcn_mfma_f32_16x16x32_bf16(qf0, kf0, S, 0, 0, 0);
      S = __builtin_amdgcn_mfma_f32_16x16x32_bf16(qf1, kf1, S, 0, 0, 0);
      const int c0 = kt * 64 + tj * 16;
      const int prow0 = wv * 16 + lq;      // physical row for r=0; +4 per r
      if (c0 + 31 <= qa0) {
        #pragma unroll
        for (int r = 0; r < 4; ++r) {
          const float p = __builtin_amdgcn_exp2f(fmaf(S[r], CE, q0a[r]));
          r0a[r] += p;
          Pt[prow0 + r * 4][tj * 16 + lm] = f2bf(p);
        }
      } else if (c0 >= qa0 + 31) {
        #pragma unroll
        for (int r = 0; r < 4; ++r) {
          const float p = __builtin_amdgcn_exp2f(fmaf(S[r], CE, q32a[r]));
          r32a[r] += p;
          Pt[prow0 + r * 4][tj * 16 + lm] = f2bf(p);
        }
      } else {
        const int kpos = c0 + lm;
        #pragma unroll
        for (int r = 0; r < 4; ++r) {
          const int rowl = wv * 16 + lq * 4 + r;
          const int dist = kpos - (qt * 64 + rowl);
          const int bin = (dist < -16 ? 0 : (dist > 16 ? 32 : dist + 16));
          const float p = __builtin_amdgcn_exp2f(fmaf(S[r], CE, qrel_s[rowl][bin]));
          if (bin == 0)       r0a[r]  += p;
          else if (bin == 32) r32a[r] += p;
          else Racc[rowl][bin] = p;      // each (row,bin 1..31) hit exactly once
          Pt[prow0 + r * 4][tj * 16 + lm] = f2bf(p);
        }
      }
    }
    __syncthreads();   // order ALL P-stores before P.V fragment reads
    bf16x8 pf0 = *(const bf16x8*)(&Pt[pread][lq * 8]);
    bf16x8 pf1 = *(const bf16x8*)(&Pt[pread][32 + lq * 8]);
    Rs = __builtin_amdgcn_mfma_f32_16x16x32_bf16(pf0, one8.v, Rs, 0, 0, 0);
    Rs = __builtin_amdgcn_mfma_f32_16x16x32_bf16(pf1, one8.v, Rs, 0, 0, 0);
    #pragma unroll
    for (int dt = 0; dt < 4; ++dt) {
      bf16x8 vf0 = *(const bf16x8*)(&Vt[dt * 16 + lm][lq * 8]);
      bf16x8 vf1 = *(const bf16x8*)(&Vt[dt * 16 + lm][32 + lq * 8]);
      Oa[dt] = __builtin_amdgcn_mfma_f32_16x16x32_bf16(pf0, vf0, Oa[dt], 0, 0, 0);
      Oa[dt] = __builtin_amdgcn_mfma_f32_16x16x32_bf16(pf1, vf1, Oa[dt], 0, 0, 0);
    }
  }

  // reduce per-lane clip-bin partials across the 16 lanes sharing each row
  #pragma unroll
  for (int r = 0; r < 4; ++r) {
    #pragma unroll
    for (int off = 1; off < 16; off <<= 1) {
      r0a[r]  += __shfl_xor(r0a[r],  off, 64);
      r32a[r] += __shfl_xor(r32a[r], off, 64);
    }
  }
  if (lm == 0) {
    #pragma unroll
    for (int r = 0; r < 4; ++r) Racc[wv * 16 + lq * 4 + r][0] = r0a[r];
  }
  __syncthreads();
  for (int i = tid; i < 64 * 32; i += 256) {
    const int rr = i >> 5, cc = i & 31;
    Pt[rr][cc] = f2bf(Racc[rr][cc]);
  }
  __syncthreads();

  bf16x8 raf = *(const bf16x8*)(&Pt[wv * 16 + lm][lq * 8]);
  #pragma unroll
  for (int dt = 0; dt < 4; ++dt) {
    bf16x8 rvb = *(const bf16x8*)(&relvT[dt * 16 + lm][lq * 8]);
    f32x4 O2 = {};
    O2 = __builtin_amdgcn_mfma_f32_16x16x32_bf16(raf, rvb, O2, 0, 0, 0);
    const float rv32 = relv[32 * 64 + dt * 16 + lm];
    #pragma unroll
    for (int r = 0; r < 4; ++r) {
      const int rowl = wv * 16 + lq * 4 + r;
      const float v = (Oa[dt][r] + O2[r] + r32a[r] * rv32) / Rs[r];
      ctx[(size_t)(tok0 + rowl) * 1024 + h * 64 + dt * 16 + lm] = f2bf(v);
    }
  }
}

// ---------------------------------------------------------------------------
// LayerNorm with residual: y = LN(x + res)*g + b -> fp32 (and optional bf16).
// float4 per thread (256 thr x 4 = 1024), row kept in registers, no LDS buf.
// ---------------------------------------------------------------------------
template<bool WB>
__global__ __launch_bounds__(256) void ln_res(
    const float* __restrict__ x, const float* __restrict__ res,
    const float* __restrict__ g, const float* __restrict__ bta,
    float* __restrict__ of, unsigned short* __restrict__ ob)
{
  const int row = blockIdx.x;
  const int tid = threadIdx.x;
  __shared__ float red[8];
  const size_t base = (size_t)row * 1024 + tid * 4;
  const float4 xv = *(const float4*)(x + base);
  const float4 rv = *(const float4*)(res + base);
  float v0 = xv.x + rv.x, v1 = xv.y + rv.y, v2 = xv.z + rv.z, v3 = xv.w + rv.w;
  float s1 = v0 + v1 + v2 + v3;
  float s2 = v0 * v0 + v1 * v1 + v2 * v2 + v3 * v3;
  #pragma unroll
  for (int off = 1; off < 64; off <<= 1) {
    s1 += __shfl_xor(s1, off, 64);
    s2 += __shfl_xor(s2, off, 64);
  }
  const int wv = tid >> 6;
  if ((tid & 63) == 0) { red[wv * 2] = s1; red[wv * 2 + 1] = s2; }
  __syncthreads();
  s1 = red[0] + red[2] + red[4] + red[6];
  s2 = red[1] + red[3] + red[5] + red[7];
  const float mean = s1 * (1.f / 1024.f);
  const float var = s2 * (1.f / 1024.f) - mean * mean;
  const float rstd = rsqrtf(var + 1e-6f);
  const float4 gv = *(const float4*)(g + tid * 4);
  const float4 bv = *(const float4*)(bta + tid * 4);
  float y0 = (v0 - mean) * rstd * gv.x + bv.x;
  float y1 = (v1 - mean) * rstd * gv.y + bv.y;
  float y2 = (v2 - mean) * rstd * gv.z + bv.z;
  float y3 = (v3 - mean) * rstd * gv.w + bv.w;
  float4 yo; yo.x = y0; yo.y = y1; yo.z = y2; yo.w = y3;
  *(float4*)(of + base) = yo;
  if (WB) {
    ushort4 o;
    o.x = f2bf(y0); o.y = f2bf(y1); o.z = f2bf(y2); o.w = f2bf(y3);
    *(ushort4*)(ob + base) = o;
  }
}

// ---------------------------------------------------------------------------
extern "C" void kernel_launch(void* const* d_in, const int* in_sizes, int n_in,
                              void* d_out, int out_size, void* d_ws, size_t ws_size,
                              hipStream_t stream) {
  (void)in_sizes; (void)n_in; (void)out_size; (void)ws_size;
  const float* q    = (const float*)d_in[0];
  const float* k    = (const float*)d_in[1];
  const float* v    = (const float*)d_in[2];
  const float* wq   = (const float*)d_in[3];
  const float* bq   = (const float*)d_in[4];
  const float* wk   = (const float*)d_in[5];
  const float* bk   = (const float*)d_in[6];
  const float* wv_  = (const float*)d_in[7];
  const float* bv   = (const float*)d_in[8];
  const float* wfc  = (const float*)d_in[9];
  const float* bfc  = (const float*)d_in[10];
  const float* w1   = (const float*)d_in[11];
  const float* b1   = (const float*)d_in[12];
  const float* w2   = (const float*)d_in[13];
  const float* b2   = (const float*)d_in[14];
  const float* ln_g = (const float*)d_in[15];
  const float* ln_b = (const float*)d_in[16];
  const float* rel_k = (const float*)d_in[17];
  const float* rel_v = (const float*)d_in[18];

  char* ws = (char*)d_ws;
  const size_t MB = 1ull << 20;
  unsigned short* WQT  = (unsigned short*)(ws + 0 * MB);
  unsigned short* WKT  = (unsigned short*)(ws + 2 * MB);
  unsigned short* WVT  = (unsigned short*)(ws + 4 * MB);
  unsigned short* WFCT = (unsigned short*)(ws + 6 * MB);
  unsigned short* W1T  = (unsigned short*)(ws + 8 * MB);    // [4096][1024]
  unsigned short* W2T  = (unsigned short*)(ws + 16 * MB);   // [1024][4096]
  unsigned short* QP   = (unsigned short*)(ws + 24 * MB);   // [24,40)
  unsigned short* KP   = (unsigned short*)(ws + 40 * MB);   // [40,56)
  unsigned short* VP   = (unsigned short*)(ws + 56 * MB);   // [56,72)
  unsigned short* QBF  = (unsigned short*)(ws + 72 * MB);   // [72,88)
  unsigned short* KBF  = (unsigned short*)(ws + 88 * MB);   // [88,104)
  unsigned short* VBF  = (unsigned short*)(ws + 104 * MB);  // [104,120)
  // lifetime reuse (all producers strictly after the region's last reader):
  unsigned short* VPT  = QBF;                               // [72,88)
  unsigned short* CTX  = KBF;                               // [88,104)
  float*          OTMP = (float*)(ws + 104 * MB);           // [104,136)
  float*          X1F  = (float*)(ws + 24 * MB);            // [24,56)
  unsigned short* X1BF = VP;                                // [56,72)
  unsigned short* HBUF = (unsigned short*)(ws + 72 * MB);   // [72,136)
  float*          Y2   = (float*)(ws + 136 * MB);           // [136,168)

  const dim3 blk(256);
  const int NTOK = 8192;

  tcast<<<dim3(32, 32), blk, 0, stream>>>(wq, WQT, 1024, 1024);
  tcast<<<dim3(32, 32), blk, 0, stream>>>(wk, WKT, 1024, 1024);
  tcast<<<dim3(32, 32), blk, 0, stream>>>(wv_, WVT, 1024, 1024);
  tcast<<<dim3(32, 32), blk, 0, stream>>>(wfc, WFCT, 1024, 1024);
  tcast<<<dim3(128, 32), blk, 0, stream>>>(w1, W1T, 1024, 4096);
  tcast<<<dim3(32, 128), blk, 0, stream>>>(w2, W2T, 4096, 1024);
  cast4<<<8192, blk, 0, stream>>>(q, QBF, NTOK * 1024);
  cast4<<<8192, blk, 0, stream>>>(k, KBF, NTOK * 1024);
  cast4<<<8192, blk, 0, stream>>>(v, VBF, NTOK * 1024);

  // fused QKV: z picks A (QBF/KBF/VBF), B (WQT/WKT/WVT), bias, C (QP/KP/VP)
  gemm_bt<0><<<dim3(8, 64, 3), blk, 0, stream>>>(
      QBF, WQT, bq, bk, bv, QP, NTOK, 1024, 1024,
      (size_t)8 * MB, (size_t)1 * MB, (size_t)8 * MB);

  vtrans<<<dim3(16, 16, 8), blk, 0, stream>>>(VP, VPT);

  attn_flash<<<dim3(16, 16, 8), blk, 0, stream>>>(QP, KP, VPT, rel_k, rel_v, CTX);

  gemm_bt<1><<<dim3(8, 64), blk, 0, stream>>>(CTX, WFCT, bfc, bfc, bfc, OTMP,
                                              NTOK, 1024, 1024, 0, 0, 0);
  ln_res<true><<<8192, blk, 0, stream>>>(OTMP, q, ln_g, ln_b, X1F, X1BF);
  gemm_bt<2><<<dim3(32, 64), blk, 0, stream>>>(X1BF, W1T, b1, b1, b1, HBUF,
                                               NTOK, 4096, 1024, 0, 0, 0);
  gemm_bt<1><<<dim3(8, 64), blk, 0, stream>>>(HBUF, W2T, b2, b2, b2, Y2,
                                              NTOK, 1024, 4096, 0, 0, 0);
  ln_res<false><<<8192, blk, 0, stream>>>(Y2, X1F, ln_g, ln_b, (float*)d_out, nullptr);
}